// Round 1
// baseline (3002.600 us; speedup 1.0000x reference)
//
#include <hip/hip_runtime.h>
#include <math.h>

static constexpr int N_NODES = 50000;
static constexpr int E_EDGES = 800000;
static constexpr int IN_F = 64;
static constexpr int H_F = 128;
static constexpr int K_C = 16;

// out[i][j] = sum_k in[i][k] * W[k][j]   (j < 128), W staged in LDS.
template<int KIN>
__global__ __launch_bounds__(128) void gemm_rows(
    const float* __restrict__ in, const float* __restrict__ W,
    float* __restrict__ out, int n) {
  __shared__ float Wl[KIN * H_F];
  for (int t = threadIdx.x; t < KIN * H_F; t += 128) Wl[t] = W[t];
  __syncthreads();
  const int j = threadIdx.x;
  const int i0 = blockIdx.x * 16;
  const int iend = (i0 + 16 < n) ? (i0 + 16) : n;
  for (int i = i0; i < iend; ++i) {
    const float* __restrict__ row = in + (size_t)i * KIN;  // wave-uniform
    float acc = 0.f;
#pragma unroll
    for (int k = 0; k < KIN; ++k) acc = fmaf(row[k], Wl[k * H_F + j], acc);
    out[(size_t)i * H_F + j] = acc;
  }
}

// agg[dst[e]][f] += t[src[e]][f] * w[e]; 32 threads/edge, 4 feats each.
__global__ __launch_bounds__(256) void scatter_add(
    const float* __restrict__ t, const int* __restrict__ src,
    const int* __restrict__ dst, const float* __restrict__ w,
    float* __restrict__ agg) {
  long gid = (long)blockIdx.x * 256 + threadIdx.x;
  int e = (int)(gid >> 5);
  if (e >= E_EDGES) return;
  int sub = ((int)gid & 31) * 4;
  int s = src[e], d = dst[e];
  float wt = w[e];
  const float4 v = *(const float4*)(t + (size_t)s * H_F + sub);
  float* base = agg + (size_t)d * H_F + sub;
  atomicAdd(base + 0, v.x * wt);
  atomicAdd(base + 1, v.y * wt);
  atomicAdd(base + 2, v.z * wt);
  atomicAdd(base + 3, v.w * wt);
}

// in-place h = relu(h + bias), one float4 per thread
__global__ __launch_bounds__(256) void bias_relu_kernel(
    float* __restrict__ buf, const float* __restrict__ bias) {
  int gid = blockIdx.x * 256 + threadIdx.x;   // N*32 threads exactly
  int f4 = gid & (H_F / 4 - 1);               // which float4 within row
  float4* p = (float4*)buf + gid;
  float4 v = *p;
  const float4 b = ((const float4*)bias)[f4];
  v.x = fmaxf(v.x + b.x, 0.f);
  v.y = fmaxf(v.y + b.y, 0.f);
  v.z = fmaxf(v.z + b.z, 0.f);
  v.w = fmaxf(v.w + b.w, 0.f);
  *p = v;
}

// Per node: s = relu(h2raw + b2) @ Wm + bm; softmax over 16; write sm; diag += sm^2
__global__ __launch_bounds__(256) void head_kernel(
    const float* __restrict__ h2raw, const float* __restrict__ b2,
    const float* __restrict__ Wm, const float* __restrict__ bm,
    float* __restrict__ sm_out, float* __restrict__ diag, int n) {
  __shared__ float Wl[H_F * K_C];   // 8 KB
  __shared__ float part[K_C];
  for (int t = threadIdx.x; t < H_F * K_C; t += 256) Wl[t] = Wm[t];
  if (threadIdx.x < K_C) part[threadIdx.x] = 0.f;
  __syncthreads();

  const int node = blockIdx.x * 16 + (threadIdx.x >> 4);
  const int c = threadIdx.x & 15;
  float acc = bm[c];
  if (node < n) {
    const float* __restrict__ hrow = h2raw + (size_t)node * H_F;
#pragma unroll 8
    for (int k = 0; k < H_F; ++k) {
      float h = fmaxf(hrow[k] + b2[k], 0.f);
      acc = fmaf(h, Wl[k * K_C + c], acc);
    }
  }
  // softmax across the 16 contiguous lanes of this node
  float mx = acc;
#pragma unroll
  for (int off = 8; off; off >>= 1) mx = fmaxf(mx, __shfl_xor(mx, off, 16));
  float ex = __expf(acc - mx);
  float sum = ex;
#pragma unroll
  for (int off = 8; off; off >>= 1) sum += __shfl_xor(sum, off, 16);
  float smv = ex / sum;
  float sq = 0.f;
  if (node < n) {
    sm_out[(size_t)node * K_C + c] = smv;
    sq = smv * smv;
  }
  atomicAdd(&part[c], sq);
  __syncthreads();
  if (threadIdx.x < K_C) atomicAdd(&diag[threadIdx.x], part[threadIdx.x]);
}

__global__ void loss_kernel(const float* __restrict__ diag, float* __restrict__ out) {
  int c = threadIdx.x;
  float v = (c < K_C) ? sqrtf(diag[c] + 1e-15f) : 0.f;
#pragma unroll
  for (int off = 8; off; off >>= 1) v += __shfl_xor(v, off, 16);
  if (c == 0) out[0] = -v / sqrtf((float)N_NODES * (float)K_C);
}

extern "C" void kernel_launch(void* const* d_in, const int* in_sizes, int n_in,
                              void* d_out, int out_size, void* d_ws, size_t ws_size,
                              hipStream_t stream) {
  const float* x  = (const float*)d_in[0];
  const int*   ei = (const int*)d_in[1];
  const float* ew = (const float*)d_in[2];
  const float* W1 = (const float*)d_in[3];
  const float* b1 = (const float*)d_in[4];
  const float* W2 = (const float*)d_in[5];
  const float* b2 = (const float*)d_in[6];
  const float* Wm = (const float*)d_in[7];
  const float* bm = (const float*)d_in[8];
  float* out = (float*)d_out;

  const int* srcv = ei;
  const int* dstv = ei + E_EDGES;

  char* ws = (char*)d_ws;
  float* diag = (float*)ws;                   // 16 floats (1 KB pad)
  float* bufA = (float*)(ws + 1024);          // N*H floats
  float* bufB = bufA + (size_t)N_NODES * H_F; // N*H floats
  const size_t hbytes = (size_t)N_NODES * H_F * sizeof(float);

  hipMemsetAsync(diag, 0, K_C * sizeof(float), stream);

  // layer 1: t1 = x @ W1
  gemm_rows<IN_F><<<N_NODES / 16, 128, 0, stream>>>(x, W1, bufA, N_NODES);
  hipMemsetAsync(bufB, 0, hbytes, stream);
  scatter_add<<<(E_EDGES * 32) / 256, 256, 0, stream>>>(bufA, srcv, dstv, ew, bufB);
  bias_relu_kernel<<<(N_NODES * (H_F / 4)) / 256, 256, 0, stream>>>(bufB, b1);

  // layer 2: t2 = h1 @ W2
  gemm_rows<H_F><<<N_NODES / 16, 128, 0, stream>>>(bufB, W2, bufA, N_NODES);
  hipMemsetAsync(bufB, 0, hbytes, stream);
  scatter_add<<<(E_EDGES * 32) / 256, 256, 0, stream>>>(bufA, srcv, dstv, ew, bufB);

  // head: s = relu(agg2+b2) @ Wm + bm -> softmax -> sm, diag
  head_kernel<<<N_NODES / 16, 256, 0, stream>>>(bufB, b2, Wm, bm, out, diag, N_NODES);
  loss_kernel<<<1, 64, 0, stream>>>(diag, out + (size_t)N_NODES * K_C);
}

// Round 2
// 659.011 us; speedup vs baseline: 4.5562x; 4.5562x over previous
//
#include <hip/hip_runtime.h>
#include <math.h>

static constexpr int N_NODES = 50000;
static constexpr int E_EDGES = 800000;
static constexpr int IN_F = 64;
static constexpr int H_F = 128;
static constexpr int K_C = 16;

// ---------------- CSR build (counting sort by dst) ----------------

__global__ __launch_bounds__(256) void hist_kernel(
    const int* __restrict__ dst, int* __restrict__ deg) {
  int e = blockIdx.x * 256 + threadIdx.x;
  if (e < E_EDGES) atomicAdd(&deg[dst[e]], 1);
}

// Single block of 1024 threads: exclusive scan of deg[N] -> off[N] (+off[N]=E),
// and writes cursor[i]=off[i]. deg and cursor may alias.
__global__ __launch_bounds__(1024) void scan_kernel(
    const int* __restrict__ deg, int* __restrict__ off, int* __restrict__ cursor) {
  __shared__ int part[1024];
  const int CHUNK = (N_NODES + 1023) / 1024;  // 49
  const int tid = threadIdx.x;
  const int lo = tid * CHUNK;
  const int hi = (lo + CHUNK < N_NODES) ? lo + CHUNK : N_NODES;
  int s = 0;
  for (int i = lo; i < hi; ++i) s += deg[i];
  part[tid] = s;
  __syncthreads();
  for (int d = 1; d < 1024; d <<= 1) {
    int v = (tid >= d) ? part[tid - d] : 0;
    __syncthreads();
    part[tid] += v;
    __syncthreads();
  }
  int base = (tid == 0) ? 0 : part[tid - 1];
  for (int i = lo; i < hi; ++i) {
    int d = deg[i];          // read before aliased write
    off[i] = base;
    cursor[i] = base;
    base += d;
  }
  if (tid == 0) off[N_NODES] = E_EDGES;
}

__global__ __launch_bounds__(256) void fill_kernel(
    const int* __restrict__ src, const int* __restrict__ dst,
    const float* __restrict__ w, int* __restrict__ cursor, int2* __restrict__ csr) {
  int e = blockIdx.x * 256 + threadIdx.x;
  if (e >= E_EDGES) return;
  int d = dst[e];
  int pos = atomicAdd(&cursor[d], 1);
  csr[pos] = make_int2(src[e], __float_as_int(w[e]));
}

// ---------------- dense transform ----------------
// out[i][j] = sum_k in[i][k] * W[k][j]   (j < 128), W staged in LDS.
template<int KIN>
__global__ __launch_bounds__(128) void gemm_rows(
    const float* __restrict__ in, const float* __restrict__ W,
    float* __restrict__ out, int n) {
  __shared__ float Wl[KIN * H_F];
  for (int t = threadIdx.x; t < KIN * H_F; t += 128) Wl[t] = W[t];
  __syncthreads();
  const int j = threadIdx.x;
  const int i0 = blockIdx.x * 16;
  const int iend = (i0 + 16 < n) ? (i0 + 16) : n;
  for (int i = i0; i < iend; ++i) {
    const float* __restrict__ row = in + (size_t)i * KIN;  // wave-uniform
    float acc = 0.f;
#pragma unroll
    for (int k = 0; k < KIN; ++k) acc = fmaf(row[k], Wl[k * H_F + j], acc);
    out[(size_t)i * H_F + j] = acc;
  }
}

// ---------------- gather aggregation ----------------
// One 64-lane wave per node; float2 (=128 feats) accumulator in registers.
template<bool RELU_BIAS>
__global__ __launch_bounds__(256) void gather_agg(
    const float* __restrict__ t, const int* __restrict__ off,
    const int2* __restrict__ csr, const float* __restrict__ bias,
    float* __restrict__ outb) {
  const int node = blockIdx.x * 4 + (threadIdx.x >> 6);  // N divisible by 4
  const int lane = threadIdx.x & 63;
  const int p0 = off[node];
  const int p1 = off[node + 1];
  float2 acc = make_float2(0.f, 0.f);
  for (int p = p0; p < p1; ++p) {
    const int2 ew = csr[p];                      // wave-uniform 8B
    const float wt = __int_as_float(ew.y);
    const float2 v = ((const float2*)(t + (size_t)ew.x * H_F))[lane];
    acc.x = fmaf(v.x, wt, acc.x);
    acc.y = fmaf(v.y, wt, acc.y);
  }
  if (RELU_BIAS) {
    const float2 b = ((const float2*)bias)[lane];
    acc.x = fmaxf(acc.x + b.x, 0.f);
    acc.y = fmaxf(acc.y + b.y, 0.f);
  }
  ((float2*)(outb + (size_t)node * H_F))[lane] = acc;
}

// ---------------- head: relu(h+b2) @ Wm + bm -> softmax -> sm, diag ----------------
__global__ __launch_bounds__(256) void head_kernel(
    const float* __restrict__ h2raw, const float* __restrict__ b2,
    const float* __restrict__ Wm, const float* __restrict__ bm,
    float* __restrict__ sm_out, float* __restrict__ diag, int n) {
  __shared__ float Wl[H_F * K_C];   // 8 KB
  __shared__ float part[K_C];
  for (int t = threadIdx.x; t < H_F * K_C; t += 256) Wl[t] = Wm[t];
  if (threadIdx.x < K_C) part[threadIdx.x] = 0.f;
  __syncthreads();

  const int node = blockIdx.x * 16 + (threadIdx.x >> 4);
  const int c = threadIdx.x & 15;
  float acc = bm[c];
  if (node < n) {
    const float* __restrict__ hrow = h2raw + (size_t)node * H_F;
#pragma unroll 8
    for (int k = 0; k < H_F; ++k) {
      float h = fmaxf(hrow[k] + b2[k], 0.f);
      acc = fmaf(h, Wl[k * K_C + c], acc);
    }
  }
  float mx = acc;
#pragma unroll
  for (int off = 8; off; off >>= 1) mx = fmaxf(mx, __shfl_xor(mx, off, 16));
  float ex = __expf(acc - mx);
  float sum = ex;
#pragma unroll
  for (int off = 8; off; off >>= 1) sum += __shfl_xor(sum, off, 16);
  float smv = ex / sum;
  float sq = 0.f;
  if (node < n) {
    sm_out[(size_t)node * K_C + c] = smv;
    sq = smv * smv;
  }
  atomicAdd(&part[c], sq);
  __syncthreads();
  if (threadIdx.x < K_C) atomicAdd(&diag[threadIdx.x], part[threadIdx.x]);
}

__global__ void loss_kernel(const float* __restrict__ diag, float* __restrict__ out) {
  int c = threadIdx.x;
  float v = (c < K_C) ? sqrtf(diag[c] + 1e-15f) : 0.f;
#pragma unroll
  for (int off = 8; off; off >>= 1) v += __shfl_xor(v, off, 16);
  if (c == 0) out[0] = -v / sqrtf((float)N_NODES * (float)K_C);
}

extern "C" void kernel_launch(void* const* d_in, const int* in_sizes, int n_in,
                              void* d_out, int out_size, void* d_ws, size_t ws_size,
                              hipStream_t stream) {
  const float* x  = (const float*)d_in[0];
  const int*   ei = (const int*)d_in[1];
  const float* ew = (const float*)d_in[2];
  const float* W1 = (const float*)d_in[3];
  const float* b1 = (const float*)d_in[4];
  const float* W2 = (const float*)d_in[5];
  const float* b2 = (const float*)d_in[6];
  const float* Wm = (const float*)d_in[7];
  const float* bm = (const float*)d_in[8];
  float* out = (float*)d_out;

  const int* srcv = ei;
  const int* dstv = ei + E_EDGES;

  // workspace layout
  char* ws = (char*)d_ws;
  float* diag  = (float*)ws;                          // 64 B (pad to 256)
  int*   off   = (int*)(ws + 256);                    // N+1 ints
  int*   cursor= off + (N_NODES + 64);                // N ints (also deg)
  int2*  csr   = (int2*)(cursor + N_NODES);           // E int2 = 6.4 MB
  float* bufA  = (float*)((char*)(csr + E_EDGES));    // N*H floats
  float* bufB  = bufA + (size_t)N_NODES * H_F;        // N*H floats

  hipMemsetAsync(diag, 0, K_C * sizeof(float), stream);
  hipMemsetAsync(cursor, 0, N_NODES * sizeof(int), stream);

  // CSR build
  hist_kernel<<<(E_EDGES + 255) / 256, 256, 0, stream>>>(dstv, cursor);
  scan_kernel<<<1, 1024, 0, stream>>>(cursor, off, cursor);
  fill_kernel<<<(E_EDGES + 255) / 256, 256, 0, stream>>>(srcv, dstv, ew, cursor, csr);

  // layer 1
  gemm_rows<IN_F><<<N_NODES / 16, 128, 0, stream>>>(x, W1, bufA, N_NODES);
  gather_agg<true><<<N_NODES / 4, 256, 0, stream>>>(bufA, off, csr, b1, bufB);

  // layer 2
  gemm_rows<H_F><<<N_NODES / 16, 128, 0, stream>>>(bufB, W2, bufA, N_NODES);
  gather_agg<false><<<N_NODES / 4, 256, 0, stream>>>(bufA, off, csr, b1, bufB);

  // head
  head_kernel<<<N_NODES / 16, 256, 0, stream>>>(bufB, b2, Wm, bm, out, diag, N_NODES);
  loss_kernel<<<1, 64, 0, stream>>>(diag, out + (size_t)N_NODES * K_C);
}

// Round 3
// 492.989 us; speedup vs baseline: 6.0906x; 1.3368x over previous
//
#include <hip/hip_runtime.h>
#include <math.h>

static constexpr int N_NODES = 50000;
static constexpr int E_EDGES = 800000;
static constexpr int IN_F = 64;
static constexpr int H_F = 128;
static constexpr int K_C = 16;

// ---------------- CSR build (counting sort by dst) ----------------

__global__ __launch_bounds__(256) void hist_kernel(
    const int* __restrict__ dst, int* __restrict__ deg) {
  int e = blockIdx.x * 256 + threadIdx.x;
  if (e < E_EDGES) atomicAdd(&deg[dst[e]], 1);
}

__global__ __launch_bounds__(1024) void scan_kernel(
    const int* __restrict__ deg, int* __restrict__ off, int* __restrict__ cursor) {
  __shared__ int part[1024];
  const int CHUNK = (N_NODES + 1023) / 1024;  // 49
  const int tid = threadIdx.x;
  const int lo = tid * CHUNK;
  const int hi = (lo + CHUNK < N_NODES) ? lo + CHUNK : N_NODES;
  int s = 0;
  for (int i = lo; i < hi; ++i) s += deg[i];
  part[tid] = s;
  __syncthreads();
  for (int d = 1; d < 1024; d <<= 1) {
    int v = (tid >= d) ? part[tid - d] : 0;
    __syncthreads();
    part[tid] += v;
    __syncthreads();
  }
  int base = (tid == 0) ? 0 : part[tid - 1];
  for (int i = lo; i < hi; ++i) {
    int d = deg[i];          // read before aliased write
    off[i] = base;
    cursor[i] = base;
    base += d;
  }
  if (tid == 0) off[N_NODES] = E_EDGES;
}

__global__ __launch_bounds__(256) void fill_kernel(
    const int* __restrict__ src, const int* __restrict__ dst,
    const float* __restrict__ w, int* __restrict__ cursor, int2* __restrict__ csr) {
  int e = blockIdx.x * 256 + threadIdx.x;
  if (e >= E_EDGES) return;
  int d = dst[e];
  int pos = atomicAdd(&cursor[d], 1);
  csr[pos] = make_int2(src[e], __float_as_int(w[e]));
}

// ---------------- dense transform ----------------
// Block: 256 threads -> 32 rows x 128 cols. X tile staged in LDS (row-major);
// W read from global (L2-resident). 16 independent accumulators per thread.
template<int KIN>
__global__ __launch_bounds__(256) void gemm_rows(
    const float* __restrict__ in, const float* __restrict__ W,
    float* __restrict__ out, int n) {
  constexpr int ROWS = 32;
  __shared__ float Xs[ROWS * KIN];
  const int i0 = blockIdx.x * ROWS;
  const int nrow = (n - i0 < ROWS) ? (n - i0) : ROWS;
  for (int t = threadIdx.x; t < nrow * (KIN / 4); t += 256)
    ((float4*)Xs)[t] = ((const float4*)(in + (size_t)i0 * KIN))[t];
  __syncthreads();

  const int j = threadIdx.x & 127;
  const int rg = (threadIdx.x >> 7) * 16;
  float acc[16];
#pragma unroll
  for (int r = 0; r < 16; ++r) acc[r] = 0.f;

  for (int k4 = 0; k4 < KIN / 4; ++k4) {
    const int k = k4 * 4;
    float4 wv;
    wv.x = W[(k + 0) * H_F + j];
    wv.y = W[(k + 1) * H_F + j];
    wv.z = W[(k + 2) * H_F + j];
    wv.w = W[(k + 3) * H_F + j];
#pragma unroll
    for (int r = 0; r < 16; ++r) {
      const float4 xv = *(const float4*)(Xs + (rg + r) * KIN + k);  // wave-uniform
      acc[r] = fmaf(xv.x, wv.x, acc[r]);
      acc[r] = fmaf(xv.y, wv.y, acc[r]);
      acc[r] = fmaf(xv.z, wv.z, acc[r]);
      acc[r] = fmaf(xv.w, wv.w, acc[r]);
    }
  }
#pragma unroll
  for (int r = 0; r < 16; ++r) {
    const int i = i0 + rg + r;
    if (i < n) out[(size_t)i * H_F + j] = acc[r];
  }
}

// ---------------- gather aggregation ----------------
template<bool RELU_BIAS>
__global__ __launch_bounds__(256) void gather_agg(
    const float* __restrict__ t, const int* __restrict__ off,
    const int2* __restrict__ csr, const float* __restrict__ bias,
    float* __restrict__ outb) {
  const int node = blockIdx.x * 4 + (threadIdx.x >> 6);  // N divisible by 4
  const int lane = threadIdx.x & 63;
  const int p0 = off[node];
  const int p1 = off[node + 1];
  float2 acc = make_float2(0.f, 0.f);
  for (int p = p0; p < p1; ++p) {
    const int2 ew = csr[p];                      // wave-uniform 8B
    const float wt = __int_as_float(ew.y);
    const float2 v = ((const float2*)(t + (size_t)ew.x * H_F))[lane];
    acc.x = fmaf(v.x, wt, acc.x);
    acc.y = fmaf(v.y, wt, acc.y);
  }
  if (RELU_BIAS) {
    const float2 b = ((const float2*)bias)[lane];
    acc.x = fmaxf(acc.x + b.x, 0.f);
    acc.y = fmaxf(acc.y + b.y, 0.f);
  }
  ((float2*)(outb + (size_t)node * H_F))[lane] = acc;
}

// ---------------- head ----------------
__global__ __launch_bounds__(256) void head_kernel(
    const float* __restrict__ h2raw, const float* __restrict__ b2,
    const float* __restrict__ Wm, const float* __restrict__ bm,
    float* __restrict__ sm_out, float* __restrict__ diag, int n) {
  __shared__ float Wl[H_F * K_C];   // 8 KB
  __shared__ float part[K_C];
  for (int t = threadIdx.x; t < H_F * K_C; t += 256) Wl[t] = Wm[t];
  if (threadIdx.x < K_C) part[threadIdx.x] = 0.f;
  __syncthreads();

  const int node = blockIdx.x * 16 + (threadIdx.x >> 4);
  const int c = threadIdx.x & 15;
  float acc = bm[c];
  if (node < n) {
    const float* __restrict__ hrow = h2raw + (size_t)node * H_F;
#pragma unroll 8
    for (int k = 0; k < H_F; ++k) {
      float h = fmaxf(hrow[k] + b2[k], 0.f);
      acc = fmaf(h, Wl[k * K_C + c], acc);
    }
  }
  float mx = acc;
#pragma unroll
  for (int off = 8; off; off >>= 1) mx = fmaxf(mx, __shfl_xor(mx, off, 16));
  float ex = __expf(acc - mx);
  float sum = ex;
#pragma unroll
  for (int off = 8; off; off >>= 1) sum += __shfl_xor(sum, off, 16);
  float smv = ex / sum;
  float sq = 0.f;
  if (node < n) {
    sm_out[(size_t)node * K_C + c] = smv;
    sq = smv * smv;
  }
  atomicAdd(&part[c], sq);
  __syncthreads();
  if (threadIdx.x < K_C) atomicAdd(&diag[threadIdx.x], part[threadIdx.x]);
}

__global__ void loss_kernel(const float* __restrict__ diag, float* __restrict__ out) {
  int c = threadIdx.x;
  float v = (c < K_C) ? sqrtf(diag[c] + 1e-15f) : 0.f;
#pragma unroll
  for (int off = 8; off; off >>= 1) v += __shfl_xor(v, off, 16);
  if (c == 0) out[0] = -v / sqrtf((float)N_NODES * (float)K_C);
}

extern "C" void kernel_launch(void* const* d_in, const int* in_sizes, int n_in,
                              void* d_out, int out_size, void* d_ws, size_t ws_size,
                              hipStream_t stream) {
  const float* x  = (const float*)d_in[0];
  const int*   ei = (const int*)d_in[1];
  const float* ew = (const float*)d_in[2];
  const float* W1 = (const float*)d_in[3];
  const float* b1 = (const float*)d_in[4];
  const float* W2 = (const float*)d_in[5];
  const float* b2 = (const float*)d_in[6];
  const float* Wm = (const float*)d_in[7];
  const float* bm = (const float*)d_in[8];
  float* out = (float*)d_out;

  const int* srcv = ei;
  const int* dstv = ei + E_EDGES;

  char* ws = (char*)d_ws;
  float* diag  = (float*)ws;                          // 64 B (pad to 256)
  int*   off   = (int*)(ws + 256);                    // N+1 ints
  int*   cursor= off + (N_NODES + 64);                // N ints (also deg)
  int2*  csr   = (int2*)(cursor + N_NODES);           // E int2 = 6.4 MB
  float* bufA  = (float*)((char*)(csr + E_EDGES));    // N*H floats
  float* bufB  = bufA + (size_t)N_NODES * H_F;        // N*H floats

  hipMemsetAsync(diag, 0, K_C * sizeof(float), stream);
  hipMemsetAsync(cursor, 0, N_NODES * sizeof(int), stream);

  // CSR build
  hist_kernel<<<(E_EDGES + 255) / 256, 256, 0, stream>>>(dstv, cursor);
  scan_kernel<<<1, 1024, 0, stream>>>(cursor, off, cursor);
  fill_kernel<<<(E_EDGES + 255) / 256, 256, 0, stream>>>(srcv, dstv, ew, cursor, csr);

  // layer 1
  gemm_rows<IN_F><<<(N_NODES + 31) / 32, 256, 0, stream>>>(x, W1, bufA, N_NODES);
  gather_agg<true><<<N_NODES / 4, 256, 0, stream>>>(bufA, off, csr, b1, bufB);

  // layer 2
  gemm_rows<H_F><<<(N_NODES + 31) / 32, 256, 0, stream>>>(bufB, W2, bufA, N_NODES);
  gather_agg<false><<<N_NODES / 4, 256, 0, stream>>>(bufA, off, csr, b1, bufB);

  // head
  head_kernel<<<(N_NODES + 15) / 16, 256, 0, stream>>>(bufB, b2, Wm, bm, out, diag, N_NODES);
  loss_kernel<<<1, 64, 0, stream>>>(diag, out + (size_t)N_NODES * K_C);
}

// Round 4
// 389.370 us; speedup vs baseline: 7.7114x; 1.2661x over previous
//
#include <hip/hip_runtime.h>
#include <math.h>

static constexpr int N_NODES = 50000;
static constexpr int E_EDGES = 800000;
static constexpr int IN_F = 64;
static constexpr int H_F = 128;
static constexpr int K_C = 16;
static constexpr int SCAN_B = 1024;
static constexpr int NB = (N_NODES + SCAN_B - 1) / SCAN_B;   // 49

// ---------------- CSR build (counting sort by dst) ----------------

__global__ __launch_bounds__(256) void hist_kernel(
    const int* __restrict__ dst, int* __restrict__ deg) {
  int e = blockIdx.x * 256 + threadIdx.x;
  if (e < E_EDGES) atomicAdd(&deg[dst[e]], 1);
}

// Phase A: per-block exclusive scan of deg into off(local), block sums out.
__global__ __launch_bounds__(1024) void scan_local(
    const int* __restrict__ deg, int* __restrict__ off, int* __restrict__ blockSum) {
  __shared__ int part[SCAN_B];
  const int tid = threadIdx.x;
  const int i = blockIdx.x * SCAN_B + tid;
  const int v = (i < N_NODES) ? deg[i] : 0;
  part[tid] = v;
  __syncthreads();
  for (int d = 1; d < SCAN_B; d <<= 1) {
    int add = (tid >= d) ? part[tid - d] : 0;
    __syncthreads();
    part[tid] += add;
    __syncthreads();
  }
  if (i < N_NODES) off[i] = part[tid] - v;           // exclusive, block-local
  if (tid == SCAN_B - 1) blockSum[blockIdx.x] = part[tid];
}

// Phase B: one wave scans NB (<=64) block sums in place -> exclusive bases.
__global__ __launch_bounds__(64) void scan_block(int* __restrict__ blockSum) {
  const int t = threadIdx.x;
  int v = (t < NB) ? blockSum[t] : 0;
  int inc = v;
#pragma unroll
  for (int d = 1; d < 64; d <<= 1) {
    int u = __shfl_up(inc, d);
    if (t >= d) inc += u;
  }
  if (t < NB) blockSum[t] = inc - v;                 // exclusive base
}

// Phase C: add block base; mirror into cursor; off[N]=E.
__global__ __launch_bounds__(1024) void add_base(
    int* __restrict__ off, const int* __restrict__ blockSum, int* __restrict__ cursor) {
  const int i = blockIdx.x * SCAN_B + threadIdx.x;
  if (i < N_NODES) {
    int o = off[i] + blockSum[blockIdx.x];
    off[i] = o;
    cursor[i] = o;
  }
  if (i == 0) off[N_NODES] = E_EDGES;
}

__global__ __launch_bounds__(256) void fill_kernel(
    const int* __restrict__ src, const int* __restrict__ dst,
    const float* __restrict__ w, int* __restrict__ cursor, int2* __restrict__ csr) {
  int e = blockIdx.x * 256 + threadIdx.x;
  if (e >= E_EDGES) return;
  int d = dst[e];
  int pos = atomicAdd(&cursor[d], 1);
  csr[pos] = make_int2(src[e], __float_as_int(w[e]));
}

// ---------------- dense transform ----------------
// Block: 256 threads -> 32 rows x 128 cols. X tile staged in LDS (row-major);
// W read from global (L2-resident). 16 independent accumulators per thread.
template<int KIN>
__global__ __launch_bounds__(256) void gemm_rows(
    const float* __restrict__ in, const float* __restrict__ W,
    float* __restrict__ out, int n) {
  constexpr int ROWS = 32;
  __shared__ float Xs[ROWS * KIN];
  const int i0 = blockIdx.x * ROWS;
  const int nrow = (n - i0 < ROWS) ? (n - i0) : ROWS;
  for (int t = threadIdx.x; t < nrow * (KIN / 4); t += 256)
    ((float4*)Xs)[t] = ((const float4*)(in + (size_t)i0 * KIN))[t];
  __syncthreads();

  const int j = threadIdx.x & 127;
  const int rg = (threadIdx.x >> 7) * 16;
  float acc[16];
#pragma unroll
  for (int r = 0; r < 16; ++r) acc[r] = 0.f;

  for (int k4 = 0; k4 < KIN / 4; ++k4) {
    const int k = k4 * 4;
    float4 wv;
    wv.x = W[(k + 0) * H_F + j];
    wv.y = W[(k + 1) * H_F + j];
    wv.z = W[(k + 2) * H_F + j];
    wv.w = W[(k + 3) * H_F + j];
#pragma unroll
    for (int r = 0; r < 16; ++r) {
      const float4 xv = *(const float4*)(Xs + (rg + r) * KIN + k);  // wave-uniform
      acc[r] = fmaf(xv.x, wv.x, acc[r]);
      acc[r] = fmaf(xv.y, wv.y, acc[r]);
      acc[r] = fmaf(xv.z, wv.z, acc[r]);
      acc[r] = fmaf(xv.w, wv.w, acc[r]);
    }
  }
#pragma unroll
  for (int r = 0; r < 16; ++r) {
    const int i = i0 + rg + r;
    if (i < n) out[(size_t)i * H_F + j] = acc[r];
  }
}

// ---------------- gather aggregation ----------------
template<bool RELU_BIAS>
__global__ __launch_bounds__(256) void gather_agg(
    const float* __restrict__ t, const int* __restrict__ off,
    const int2* __restrict__ csr, const float* __restrict__ bias,
    float* __restrict__ outb) {
  const int node = blockIdx.x * 4 + (threadIdx.x >> 6);  // N divisible by 4
  const int lane = threadIdx.x & 63;
  const int p0 = off[node];
  const int p1 = off[node + 1];
  float2 acc = make_float2(0.f, 0.f);
  for (int p = p0; p < p1; ++p) {
    const int2 ew = csr[p];                      // wave-uniform 8B
    const float wt = __int_as_float(ew.y);
    const float2 v = ((const float2*)(t + (size_t)ew.x * H_F))[lane];
    acc.x = fmaf(v.x, wt, acc.x);
    acc.y = fmaf(v.y, wt, acc.y);
  }
  if (RELU_BIAS) {
    const float2 b = ((const float2*)bias)[lane];
    acc.x = fmaxf(acc.x + b.x, 0.f);
    acc.y = fmaxf(acc.y + b.y, 0.f);
  }
  ((float2*)(outb + (size_t)node * H_F))[lane] = acc;
}

// ---------------- head ----------------
__global__ __launch_bounds__(256) void head_kernel(
    const float* __restrict__ h2raw, const float* __restrict__ b2,
    const float* __restrict__ Wm, const float* __restrict__ bm,
    float* __restrict__ sm_out, float* __restrict__ diag, int n) {
  __shared__ float Wl[H_F * K_C];   // 8 KB
  __shared__ float part[K_C];
  for (int t = threadIdx.x; t < H_F * K_C; t += 256) Wl[t] = Wm[t];
  if (threadIdx.x < K_C) part[threadIdx.x] = 0.f;
  __syncthreads();

  const int node = blockIdx.x * 16 + (threadIdx.x >> 4);
  const int c = threadIdx.x & 15;
  float acc = bm[c];
  if (node < n) {
    const float* __restrict__ hrow = h2raw + (size_t)node * H_F;
#pragma unroll 8
    for (int k = 0; k < H_F; ++k) {
      float h = fmaxf(hrow[k] + b2[k], 0.f);
      acc = fmaf(h, Wl[k * K_C + c], acc);
    }
  }
  float mx = acc;
#pragma unroll
  for (int off = 8; off; off >>= 1) mx = fmaxf(mx, __shfl_xor(mx, off, 16));
  float ex = __expf(acc - mx);
  float sum = ex;
#pragma unroll
  for (int off = 8; off; off >>= 1) sum += __shfl_xor(sum, off, 16);
  float smv = ex / sum;
  float sq = 0.f;
  if (node < n) {
    sm_out[(size_t)node * K_C + c] = smv;
    sq = smv * smv;
  }
  atomicAdd(&part[c], sq);
  __syncthreads();
  if (threadIdx.x < K_C) atomicAdd(&diag[threadIdx.x], part[threadIdx.x]);
}

__global__ void loss_kernel(const float* __restrict__ diag, float* __restrict__ out) {
  int c = threadIdx.x;
  float v = (c < K_C) ? sqrtf(diag[c] + 1e-15f) : 0.f;
#pragma unroll
  for (int off = 8; off; off >>= 1) v += __shfl_xor(v, off, 16);
  if (c == 0) out[0] = -v / sqrtf((float)N_NODES * (float)K_C);
}

extern "C" void kernel_launch(void* const* d_in, const int* in_sizes, int n_in,
                              void* d_out, int out_size, void* d_ws, size_t ws_size,
                              hipStream_t stream) {
  const float* x  = (const float*)d_in[0];
  const int*   ei = (const int*)d_in[1];
  const float* ew = (const float*)d_in[2];
  const float* W1 = (const float*)d_in[3];
  const float* b1 = (const float*)d_in[4];
  const float* W2 = (const float*)d_in[5];
  const float* b2 = (const float*)d_in[6];
  const float* Wm = (const float*)d_in[7];
  const float* bm = (const float*)d_in[8];
  float* out = (float*)d_out;

  const int* srcv = ei;
  const int* dstv = ei + E_EDGES;

  char* ws = (char*)d_ws;
  float* diag   = (float*)ws;                         // 16 floats
  int*   bsum   = (int*)(ws + 256);                   // 64 ints
  int*   off    = (int*)(ws + 512);                   // N+1 ints
  int*   cursor = off + (N_NODES + 64);               // N ints (also deg)
  int2*  csr    = (int2*)(cursor + N_NODES);          // E int2 = 6.4 MB
  float* bufA   = (float*)((char*)(csr + E_EDGES));   // N*H floats
  float* bufB   = bufA + (size_t)N_NODES * H_F;       // N*H floats

  hipMemsetAsync(diag, 0, K_C * sizeof(float), stream);
  hipMemsetAsync(cursor, 0, N_NODES * sizeof(int), stream);

  // CSR build
  hist_kernel<<<(E_EDGES + 255) / 256, 256, 0, stream>>>(dstv, cursor);
  scan_local<<<NB, SCAN_B, 0, stream>>>(cursor, off, bsum);
  scan_block<<<1, 64, 0, stream>>>(bsum);
  add_base<<<NB, SCAN_B, 0, stream>>>(off, bsum, cursor);
  fill_kernel<<<(E_EDGES + 255) / 256, 256, 0, stream>>>(srcv, dstv, ew, cursor, csr);

  // layer 1
  gemm_rows<IN_F><<<(N_NODES + 31) / 32, 256, 0, stream>>>(x, W1, bufA, N_NODES);
  gather_agg<true><<<N_NODES / 4, 256, 0, stream>>>(bufA, off, csr, b1, bufB);

  // layer 2
  gemm_rows<H_F><<<(N_NODES + 31) / 32, 256, 0, stream>>>(bufB, W2, bufA, N_NODES);
  gather_agg<false><<<N_NODES / 4, 256, 0, stream>>>(bufA, off, csr, b1, bufB);

  // head
  head_kernel<<<(N_NODES + 15) / 16, 256, 0, stream>>>(bufB, b2, Wm, bm, out, diag, N_NODES);
  loss_kernel<<<1, 64, 0, stream>>>(diag, out + (size_t)N_NODES * K_C);
}

// Round 5
// 318.290 us; speedup vs baseline: 9.4335x; 1.2233x over previous
//
#include <hip/hip_runtime.h>
#include <math.h>

static constexpr int N_NODES = 50000;
static constexpr int E_EDGES = 800000;
static constexpr int IN_F = 64;
static constexpr int H_F = 128;
static constexpr int K_C = 16;
static constexpr int SCAN_B = 1024;
static constexpr int NB = (N_NODES + SCAN_B - 1) / SCAN_B;   // 49

// ---------------- CSR build (counting sort by dst) ----------------

__global__ __launch_bounds__(256) void hist_kernel(
    const int* __restrict__ dst, int* __restrict__ deg) {
  int e = blockIdx.x * 256 + threadIdx.x;
  if (e < E_EDGES) atomicAdd(&deg[dst[e]], 1);
}

__global__ __launch_bounds__(1024) void scan_local(
    const int* __restrict__ deg, int* __restrict__ off, int* __restrict__ blockSum) {
  __shared__ int part[SCAN_B];
  const int tid = threadIdx.x;
  const int i = blockIdx.x * SCAN_B + tid;
  const int v = (i < N_NODES) ? deg[i] : 0;
  part[tid] = v;
  __syncthreads();
  for (int d = 1; d < SCAN_B; d <<= 1) {
    int add = (tid >= d) ? part[tid - d] : 0;
    __syncthreads();
    part[tid] += add;
    __syncthreads();
  }
  if (i < N_NODES) off[i] = part[tid] - v;           // exclusive, block-local
  if (tid == SCAN_B - 1) blockSum[blockIdx.x] = part[tid];
}

__global__ __launch_bounds__(64) void scan_block(int* __restrict__ blockSum) {
  const int t = threadIdx.x;
  int v = (t < NB) ? blockSum[t] : 0;
  int inc = v;
#pragma unroll
  for (int d = 1; d < 64; d <<= 1) {
    int u = __shfl_up(inc, d);
    if (t >= d) inc += u;
  }
  if (t < NB) blockSum[t] = inc - v;                 // exclusive base
}

__global__ __launch_bounds__(1024) void add_base(
    int* __restrict__ off, const int* __restrict__ blockSum, int* __restrict__ cursor) {
  const int i = blockIdx.x * SCAN_B + threadIdx.x;
  if (i < N_NODES) {
    int o = off[i] + blockSum[blockIdx.x];
    off[i] = o;
    cursor[i] = o;
  }
  if (i == 0) off[N_NODES] = E_EDGES;
}

__global__ __launch_bounds__(256) void fill_kernel(
    const int* __restrict__ src, const int* __restrict__ dst,
    const float* __restrict__ w, int* __restrict__ cursor, int2* __restrict__ csr) {
  int e = blockIdx.x * 256 + threadIdx.x;
  if (e >= E_EDGES) return;
  int d = dst[e];
  int pos = atomicAdd(&cursor[d], 1);
  csr[pos] = make_int2(src[e], __float_as_int(w[e]));
}

// ---------------- gather aggregation ----------------
// Layer-1 pre-aggregation over raw x: 64 feats, 1 float/lane, 4-way unroll.
__global__ __launch_bounds__(256) void gather_x(
    const float* __restrict__ t, const int* __restrict__ off,
    const int2* __restrict__ csr, float* __restrict__ outb) {
  const int node = blockIdx.x * 4 + (threadIdx.x >> 6);
  const int lane = threadIdx.x & 63;
  const int p0 = off[node], p1 = off[node + 1];
  float a0 = 0.f, a1 = 0.f;
  int p = p0;
  for (; p + 4 <= p1; p += 4) {
    const int2 e0 = csr[p], e1 = csr[p + 1], e2 = csr[p + 2], e3 = csr[p + 3];
    const float v0 = t[(size_t)e0.x * IN_F + lane];
    const float v1 = t[(size_t)e1.x * IN_F + lane];
    const float v2 = t[(size_t)e2.x * IN_F + lane];
    const float v3 = t[(size_t)e3.x * IN_F + lane];
    a0 = fmaf(v0, __int_as_float(e0.y), a0);
    a1 = fmaf(v1, __int_as_float(e1.y), a1);
    a0 = fmaf(v2, __int_as_float(e2.y), a0);
    a1 = fmaf(v3, __int_as_float(e3.y), a1);
  }
  for (; p < p1; ++p) {
    const int2 e = csr[p];
    a0 = fmaf(t[(size_t)e.x * IN_F + lane], __int_as_float(e.y), a0);
  }
  outb[(size_t)node * IN_F + lane] = a0 + a1;
}

// Layer-2 aggregation over t2: 128 feats, float2/lane, 4-way unroll.
__global__ __launch_bounds__(256) void gather_h(
    const float* __restrict__ t, const int* __restrict__ off,
    const int2* __restrict__ csr, float* __restrict__ outb) {
  const int node = blockIdx.x * 4 + (threadIdx.x >> 6);
  const int lane = threadIdx.x & 63;
  const float2* __restrict__ tb = (const float2*)t;
  const int p0 = off[node], p1 = off[node + 1];
  float2 a0 = make_float2(0.f, 0.f), a1 = make_float2(0.f, 0.f);
  int p = p0;
  for (; p + 4 <= p1; p += 4) {
    const int2 e0 = csr[p], e1 = csr[p + 1], e2 = csr[p + 2], e3 = csr[p + 3];
    const float2 v0 = tb[(size_t)e0.x * 64 + lane];
    const float2 v1 = tb[(size_t)e1.x * 64 + lane];
    const float2 v2 = tb[(size_t)e2.x * 64 + lane];
    const float2 v3 = tb[(size_t)e3.x * 64 + lane];
    const float w0 = __int_as_float(e0.y), w1 = __int_as_float(e1.y);
    const float w2 = __int_as_float(e2.y), w3 = __int_as_float(e3.y);
    a0.x = fmaf(v0.x, w0, a0.x); a0.y = fmaf(v0.y, w0, a0.y);
    a1.x = fmaf(v1.x, w1, a1.x); a1.y = fmaf(v1.y, w1, a1.y);
    a0.x = fmaf(v2.x, w2, a0.x); a0.y = fmaf(v2.y, w2, a0.y);
    a1.x = fmaf(v3.x, w3, a1.x); a1.y = fmaf(v3.y, w3, a1.y);
  }
  for (; p < p1; ++p) {
    const int2 e = csr[p];
    const float2 v = tb[(size_t)e.x * 64 + lane];
    const float w = __int_as_float(e.y);
    a0.x = fmaf(v.x, w, a0.x); a0.y = fmaf(v.y, w, a0.y);
  }
  ((float2*)outb)[(size_t)node * 64 + lane] =
      make_float2(a0.x + a1.x, a0.y + a1.y);
}

// ---------------- dense transform ----------------
// Block: 256 threads -> 32 rows x 128 cols. X tile staged in LDS (row-major);
// W read from global (L2-resident). 16 independent accumulators per thread.
template<int KIN, bool BIAS_RELU>
__global__ __launch_bounds__(256) void gemm_rows(
    const float* __restrict__ in, const float* __restrict__ W,
    const float* __restrict__ bias, float* __restrict__ out, int n) {
  constexpr int ROWS = 32;
  __shared__ float Xs[ROWS * KIN];
  const int i0 = blockIdx.x * ROWS;
  const int nrow = (n - i0 < ROWS) ? (n - i0) : ROWS;
  for (int t = threadIdx.x; t < nrow * (KIN / 4); t += 256)
    ((float4*)Xs)[t] = ((const float4*)(in + (size_t)i0 * KIN))[t];
  __syncthreads();

  const int j = threadIdx.x & 127;
  const int rg = (threadIdx.x >> 7) * 16;
  float acc[16];
#pragma unroll
  for (int r = 0; r < 16; ++r) acc[r] = 0.f;

  for (int k4 = 0; k4 < KIN / 4; ++k4) {
    const int k = k4 * 4;
    float4 wv;
    wv.x = W[(k + 0) * H_F + j];
    wv.y = W[(k + 1) * H_F + j];
    wv.z = W[(k + 2) * H_F + j];
    wv.w = W[(k + 3) * H_F + j];
#pragma unroll
    for (int r = 0; r < 16; ++r) {
      const float4 xv = *(const float4*)(Xs + (rg + r) * KIN + k);  // wave-uniform
      acc[r] = fmaf(xv.x, wv.x, acc[r]);
      acc[r] = fmaf(xv.y, wv.y, acc[r]);
      acc[r] = fmaf(xv.z, wv.z, acc[r]);
      acc[r] = fmaf(xv.w, wv.w, acc[r]);
    }
  }
  const float b = BIAS_RELU ? bias[j] : 0.f;
#pragma unroll
  for (int r = 0; r < 16; ++r) {
    const int i = i0 + rg + r;
    float v = acc[r];
    if (BIAS_RELU) v = fmaxf(v + b, 0.f);
    if (i < n) out[(size_t)i * H_F + j] = v;
  }
}

// ---------------- head ----------------
__global__ __launch_bounds__(256) void head_kernel(
    const float* __restrict__ h2raw, const float* __restrict__ b2,
    const float* __restrict__ Wm, const float* __restrict__ bm,
    float* __restrict__ sm_out, float* __restrict__ diag, int n) {
  __shared__ float Wl[H_F * K_C];   // 8 KB
  __shared__ float part[K_C];
  for (int t = threadIdx.x; t < H_F * K_C; t += 256) Wl[t] = Wm[t];
  if (threadIdx.x < K_C) part[threadIdx.x] = 0.f;
  __syncthreads();

  const int node = blockIdx.x * 16 + (threadIdx.x >> 4);
  const int c = threadIdx.x & 15;
  float acc = bm[c];
  if (node < n) {
    const float* __restrict__ hrow = h2raw + (size_t)node * H_F;
#pragma unroll 8
    for (int k = 0; k < H_F; ++k) {
      float h = fmaxf(hrow[k] + b2[k], 0.f);
      acc = fmaf(h, Wl[k * K_C + c], acc);
    }
  }
  float mx = acc;
#pragma unroll
  for (int off = 8; off; off >>= 1) mx = fmaxf(mx, __shfl_xor(mx, off, 16));
  float ex = __expf(acc - mx);
  float sum = ex;
#pragma unroll
  for (int off = 8; off; off >>= 1) sum += __shfl_xor(sum, off, 16);
  float smv = ex / sum;
  float sq = 0.f;
  if (node < n) {
    sm_out[(size_t)node * K_C + c] = smv;
    sq = smv * smv;
  }
  atomicAdd(&part[c], sq);
  __syncthreads();
  if (threadIdx.x < K_C) atomicAdd(&diag[threadIdx.x], part[threadIdx.x]);
}

__global__ void loss_kernel(const float* __restrict__ diag, float* __restrict__ out) {
  int c = threadIdx.x;
  float v = (c < K_C) ? sqrtf(diag[c] + 1e-15f) : 0.f;
#pragma unroll
  for (int off = 8; off; off >>= 1) v += __shfl_xor(v, off, 16);
  if (c == 0) out[0] = -v / sqrtf((float)N_NODES * (float)K_C);
}

extern "C" void kernel_launch(void* const* d_in, const int* in_sizes, int n_in,
                              void* d_out, int out_size, void* d_ws, size_t ws_size,
                              hipStream_t stream) {
  const float* x  = (const float*)d_in[0];
  const int*   ei = (const int*)d_in[1];
  const float* ew = (const float*)d_in[2];
  const float* W1 = (const float*)d_in[3];
  const float* b1 = (const float*)d_in[4];
  const float* W2 = (const float*)d_in[5];
  const float* b2 = (const float*)d_in[6];
  const float* Wm = (const float*)d_in[7];
  const float* bm = (const float*)d_in[8];
  float* out = (float*)d_out;

  const int* srcv = ei;
  const int* dstv = ei + E_EDGES;

  char* ws = (char*)d_ws;
  float* diag   = (float*)ws;                         // 16 floats
  int*   bsum   = (int*)(ws + 256);                   // 64 ints
  int*   off    = (int*)(ws + 512);                   // N+1 ints
  int*   cursor = off + (N_NODES + 64);               // N ints (also deg)
  int2*  csr    = (int2*)(cursor + N_NODES);          // E int2 = 6.4 MB
  float* bufA   = (float*)((char*)(csr + E_EDGES));   // N*H floats
  float* bufB   = bufA + (size_t)N_NODES * H_F;       // N*H floats

  hipMemsetAsync(diag, 0, K_C * sizeof(float), stream);
  hipMemsetAsync(cursor, 0, N_NODES * sizeof(int), stream);

  // CSR build
  hist_kernel<<<(E_EDGES + 255) / 256, 256, 0, stream>>>(dstv, cursor);
  scan_local<<<NB, SCAN_B, 0, stream>>>(cursor, off, bsum);
  scan_block<<<1, 64, 0, stream>>>(bsum);
  add_base<<<NB, SCAN_B, 0, stream>>>(off, bsum, cursor);
  fill_kernel<<<(E_EDGES + 255) / 256, 256, 0, stream>>>(srcv, dstv, ew, cursor, csr);

  // layer 1 (reordered: aggregate raw x, then transform + bias + relu)
  gather_x<<<N_NODES / 4, 256, 0, stream>>>(x, off, csr, bufA);
  gemm_rows<IN_F, true><<<(N_NODES + 31) / 32, 256, 0, stream>>>(bufA, W1, b1, bufB, N_NODES);

  // layer 2: t2 = h1 @ W2, then aggregate (b2+relu applied in head)
  gemm_rows<H_F, false><<<(N_NODES + 31) / 32, 256, 0, stream>>>(bufB, W2, nullptr, bufA, N_NODES);
  gather_h<<<N_NODES / 4, 256, 0, stream>>>(bufA, off, csr, bufB);

  // head
  head_kernel<<<(N_NODES + 15) / 16, 256, 0, stream>>>(bufB, b2, Wm, bm, out, diag, N_NODES);
  loss_kernel<<<1, 64, 0, stream>>>(diag, out + (size_t)N_NODES * K_C);
}

// Round 6
// 295.564 us; speedup vs baseline: 10.1589x; 1.0769x over previous
//
#include <hip/hip_runtime.h>
#include <hip/hip_fp16.h>
#include <math.h>
#include <type_traits>

static constexpr int N_NODES = 50000;
static constexpr int E_EDGES = 800000;
static constexpr int IN_F = 64;
static constexpr int H_F = 128;
static constexpr int K_C = 16;
static constexpr int SCAN_B = 1024;
static constexpr int NB = (N_NODES + SCAN_B - 1) / SCAN_B;   // 49

// ---------------- CSR build (counting sort by dst) ----------------

__global__ __launch_bounds__(256) void hist_kernel(
    const int* __restrict__ dst, int* __restrict__ deg) {
  int e = blockIdx.x * 256 + threadIdx.x;
  if (e < E_EDGES) atomicAdd(&deg[dst[e]], 1);
}

__global__ __launch_bounds__(1024) void scan_local(
    const int* __restrict__ deg, int* __restrict__ off, int* __restrict__ blockSum) {
  __shared__ int part[SCAN_B];
  const int tid = threadIdx.x;
  const int i = blockIdx.x * SCAN_B + tid;
  const int v = (i < N_NODES) ? deg[i] : 0;
  part[tid] = v;
  __syncthreads();
  for (int d = 1; d < SCAN_B; d <<= 1) {
    int add = (tid >= d) ? part[tid - d] : 0;
    __syncthreads();
    part[tid] += add;
    __syncthreads();
  }
  if (i < N_NODES) off[i] = part[tid] - v;           // exclusive, block-local
  if (tid == SCAN_B - 1) blockSum[blockIdx.x] = part[tid];
}

__global__ __launch_bounds__(64) void scan_block(int* __restrict__ blockSum) {
  const int t = threadIdx.x;
  int v = (t < NB) ? blockSum[t] : 0;
  int inc = v;
#pragma unroll
  for (int d = 1; d < 64; d <<= 1) {
    int u = __shfl_up(inc, d);
    if (t >= d) inc += u;
  }
  if (t < NB) blockSum[t] = inc - v;                 // exclusive base
}

__global__ __launch_bounds__(1024) void add_base(
    int* __restrict__ off, const int* __restrict__ blockSum, int* __restrict__ cursor) {
  const int i = blockIdx.x * SCAN_B + threadIdx.x;
  if (i < N_NODES) {
    int o = off[i] + blockSum[blockIdx.x];
    off[i] = o;
    cursor[i] = o;
  }
  if (i == 0) off[N_NODES] = E_EDGES;
}

__global__ __launch_bounds__(256) void fill_kernel(
    const int* __restrict__ src, const int* __restrict__ dst,
    const float* __restrict__ w, int* __restrict__ cursor, int2* __restrict__ csr) {
  int e = blockIdx.x * 256 + threadIdx.x;
  if (e >= E_EDGES) return;
  int d = dst[e];
  int pos = atomicAdd(&cursor[d], 1);
  csr[pos] = make_int2(src[e], __float_as_int(w[e]));
}

// ---------------- fp32 -> fp16 conversion (4 elems/thread) ----------------
__global__ __launch_bounds__(256) void f2h_kernel(
    const float* __restrict__ in, __half* __restrict__ out, int n4) {
  int i = blockIdx.x * 256 + threadIdx.x;
  if (i >= n4) return;
  float4 v = ((const float4*)in)[i];
  __half2* o = (__half2*)out + (size_t)i * 2;
  o[0] = __floats2half2_rn(v.x, v.y);
  o[1] = __floats2half2_rn(v.z, v.w);
}

// ---------------- gather aggregation ----------------
// Layer-1 pre-aggregation over fp16 x: 64 feats, 1 half/lane, 8-way unroll.
__global__ __launch_bounds__(256) void gather_x(
    const __half* __restrict__ t, const int* __restrict__ off,
    const int2* __restrict__ csr, float* __restrict__ outb) {
  const int node = blockIdx.x * 4 + (threadIdx.x >> 6);
  const int lane = threadIdx.x & 63;
  const int p0 = off[node], p1 = off[node + 1];
  float a0 = 0.f, a1 = 0.f, a2 = 0.f, a3 = 0.f;
  int p = p0;
  for (; p + 8 <= p1; p += 8) {
    const int2 e0 = csr[p], e1 = csr[p + 1], e2 = csr[p + 2], e3 = csr[p + 3];
    const int2 e4 = csr[p + 4], e5 = csr[p + 5], e6 = csr[p + 6], e7 = csr[p + 7];
    const float v0 = __half2float(t[(size_t)e0.x * IN_F + lane]);
    const float v1 = __half2float(t[(size_t)e1.x * IN_F + lane]);
    const float v2 = __half2float(t[(size_t)e2.x * IN_F + lane]);
    const float v3 = __half2float(t[(size_t)e3.x * IN_F + lane]);
    const float v4 = __half2float(t[(size_t)e4.x * IN_F + lane]);
    const float v5 = __half2float(t[(size_t)e5.x * IN_F + lane]);
    const float v6 = __half2float(t[(size_t)e6.x * IN_F + lane]);
    const float v7 = __half2float(t[(size_t)e7.x * IN_F + lane]);
    a0 = fmaf(v0, __int_as_float(e0.y), a0);
    a1 = fmaf(v1, __int_as_float(e1.y), a1);
    a2 = fmaf(v2, __int_as_float(e2.y), a2);
    a3 = fmaf(v3, __int_as_float(e3.y), a3);
    a0 = fmaf(v4, __int_as_float(e4.y), a0);
    a1 = fmaf(v5, __int_as_float(e5.y), a1);
    a2 = fmaf(v6, __int_as_float(e6.y), a2);
    a3 = fmaf(v7, __int_as_float(e7.y), a3);
  }
  for (; p < p1; ++p) {
    const int2 e = csr[p];
    a0 = fmaf(__half2float(t[(size_t)e.x * IN_F + lane]), __int_as_float(e.y), a0);
  }
  outb[(size_t)node * IN_F + lane] = (a0 + a1) + (a2 + a3);
}

// Layer-2 aggregation over fp16 t2: 128 feats, half2/lane, 8-way unroll; fp16 out.
__global__ __launch_bounds__(256) void gather_h(
    const __half* __restrict__ t, const int* __restrict__ off,
    const int2* __restrict__ csr, __half* __restrict__ outb) {
  const int node = blockIdx.x * 4 + (threadIdx.x >> 6);
  const int lane = threadIdx.x & 63;
  const __half2* __restrict__ tb = (const __half2*)t;
  const int p0 = off[node], p1 = off[node + 1];
  float2 a0 = make_float2(0.f, 0.f), a1 = make_float2(0.f, 0.f);
  float2 a2 = make_float2(0.f, 0.f), a3 = make_float2(0.f, 0.f);
  int p = p0;
  for (; p + 8 <= p1; p += 8) {
    const int2 e0 = csr[p], e1 = csr[p + 1], e2 = csr[p + 2], e3 = csr[p + 3];
    const int2 e4 = csr[p + 4], e5 = csr[p + 5], e6 = csr[p + 6], e7 = csr[p + 7];
    const __half2 h0 = tb[(size_t)e0.x * 64 + lane];
    const __half2 h1 = tb[(size_t)e1.x * 64 + lane];
    const __half2 h2 = tb[(size_t)e2.x * 64 + lane];
    const __half2 h3 = tb[(size_t)e3.x * 64 + lane];
    const __half2 h4 = tb[(size_t)e4.x * 64 + lane];
    const __half2 h5 = tb[(size_t)e5.x * 64 + lane];
    const __half2 h6 = tb[(size_t)e6.x * 64 + lane];
    const __half2 h7 = tb[(size_t)e7.x * 64 + lane];
    float2 f; float w;
    f = __half22float2(h0); w = __int_as_float(e0.y);
    a0.x = fmaf(f.x, w, a0.x); a0.y = fmaf(f.y, w, a0.y);
    f = __half22float2(h1); w = __int_as_float(e1.y);
    a1.x = fmaf(f.x, w, a1.x); a1.y = fmaf(f.y, w, a1.y);
    f = __half22float2(h2); w = __int_as_float(e2.y);
    a2.x = fmaf(f.x, w, a2.x); a2.y = fmaf(f.y, w, a2.y);
    f = __half22float2(h3); w = __int_as_float(e3.y);
    a3.x = fmaf(f.x, w, a3.x); a3.y = fmaf(f.y, w, a3.y);
    f = __half22float2(h4); w = __int_as_float(e4.y);
    a0.x = fmaf(f.x, w, a0.x); a0.y = fmaf(f.y, w, a0.y);
    f = __half22float2(h5); w = __int_as_float(e5.y);
    a1.x = fmaf(f.x, w, a1.x); a1.y = fmaf(f.y, w, a1.y);
    f = __half22float2(h6); w = __int_as_float(e6.y);
    a2.x = fmaf(f.x, w, a2.x); a2.y = fmaf(f.y, w, a2.y);
    f = __half22float2(h7); w = __int_as_float(e7.y);
    a3.x = fmaf(f.x, w, a3.x); a3.y = fmaf(f.y, w, a3.y);
  }
  for (; p < p1; ++p) {
    const int2 e = csr[p];
    const float2 f = __half22float2(tb[(size_t)e.x * 64 + lane]);
    const float w = __int_as_float(e.y);
    a0.x = fmaf(f.x, w, a0.x); a0.y = fmaf(f.y, w, a0.y);
  }
  const float2 s = make_float2((a0.x + a1.x) + (a2.x + a3.x),
                               (a0.y + a1.y) + (a2.y + a3.y));
  ((__half2*)outb)[(size_t)node * 64 + lane] = __float22half2_rn(s);
}

// ---------------- dense transform ----------------
// Block: 256 threads -> 32 rows x 128 cols. X tile staged in LDS (row-major);
// W read from global (L2-resident). 16 independent accumulators per thread.
template<int KIN, bool BIAS_RELU, typename OutT>
__global__ __launch_bounds__(256) void gemm_rows(
    const float* __restrict__ in, const float* __restrict__ W,
    const float* __restrict__ bias, OutT* __restrict__ out, int n) {
  constexpr int ROWS = 32;
  __shared__ float Xs[ROWS * KIN];
  const int i0 = blockIdx.x * ROWS;
  const int nrow = (n - i0 < ROWS) ? (n - i0) : ROWS;
  for (int t = threadIdx.x; t < nrow * (KIN / 4); t += 256)
    ((float4*)Xs)[t] = ((const float4*)(in + (size_t)i0 * KIN))[t];
  __syncthreads();

  const int j = threadIdx.x & 127;
  const int rg = (threadIdx.x >> 7) * 16;
  float acc[16];
#pragma unroll
  for (int r = 0; r < 16; ++r) acc[r] = 0.f;

  for (int k4 = 0; k4 < KIN / 4; ++k4) {
    const int k = k4 * 4;
    float4 wv;
    wv.x = W[(k + 0) * H_F + j];
    wv.y = W[(k + 1) * H_F + j];
    wv.z = W[(k + 2) * H_F + j];
    wv.w = W[(k + 3) * H_F + j];
#pragma unroll
    for (int r = 0; r < 16; ++r) {
      const float4 xv = *(const float4*)(Xs + (rg + r) * KIN + k);  // wave-uniform
      acc[r] = fmaf(xv.x, wv.x, acc[r]);
      acc[r] = fmaf(xv.y, wv.y, acc[r]);
      acc[r] = fmaf(xv.z, wv.z, acc[r]);
      acc[r] = fmaf(xv.w, wv.w, acc[r]);
    }
  }
  const float b = BIAS_RELU ? bias[j] : 0.f;
#pragma unroll
  for (int r = 0; r < 16; ++r) {
    const int i = i0 + rg + r;
    float v = acc[r];
    if (BIAS_RELU) v = fmaxf(v + b, 0.f);
    if (i < n) {
      if constexpr (std::is_same<OutT, __half>::value)
        out[(size_t)i * H_F + j] = __float2half_rn(v);
      else
        out[(size_t)i * H_F + j] = v;
    }
  }
}

// ---------------- head: relu(h2+b2) @ Wm + bm -> softmax -> sm, diag ----------------
__global__ __launch_bounds__(256) void head_kernel(
    const __half* __restrict__ h2raw, const float* __restrict__ b2,
    const float* __restrict__ Wm, const float* __restrict__ bm,
    float* __restrict__ sm_out, float* __restrict__ diag, int n) {
  __shared__ float Wl[H_F * K_C];   // 8 KB
  __shared__ float b2l[H_F];
  __shared__ float part[K_C];
  for (int t = threadIdx.x; t < H_F * K_C; t += 256) Wl[t] = Wm[t];
  if (threadIdx.x < H_F) b2l[threadIdx.x] = b2[threadIdx.x];
  if (threadIdx.x < K_C) part[threadIdx.x] = 0.f;
  __syncthreads();

  const int node = blockIdx.x * 16 + (threadIdx.x >> 4);
  const int c = threadIdx.x & 15;
  float acc = bm[c];
  if (node < n) {
    const __half2* __restrict__ hrow = (const __half2*)(h2raw + (size_t)node * H_F);
#pragma unroll 8
    for (int k2 = 0; k2 < H_F / 2; ++k2) {
      const float2 hv = __half22float2(hrow[k2]);
      const float h0 = fmaxf(hv.x + b2l[2 * k2], 0.f);
      const float h1 = fmaxf(hv.y + b2l[2 * k2 + 1], 0.f);
      acc = fmaf(h0, Wl[(2 * k2) * K_C + c], acc);
      acc = fmaf(h1, Wl[(2 * k2 + 1) * K_C + c], acc);
    }
  }
  float mx = acc;
#pragma unroll
  for (int off = 8; off; off >>= 1) mx = fmaxf(mx, __shfl_xor(mx, off, 16));
  float ex = __expf(acc - mx);
  float sum = ex;
#pragma unroll
  for (int off = 8; off; off >>= 1) sum += __shfl_xor(sum, off, 16);
  float smv = ex / sum;
  float sq = 0.f;
  if (node < n) {
    sm_out[(size_t)node * K_C + c] = smv;
    sq = smv * smv;
  }
  atomicAdd(&part[c], sq);
  __syncthreads();
  if (threadIdx.x < K_C) atomicAdd(&diag[threadIdx.x], part[threadIdx.x]);
}

__global__ void loss_kernel(const float* __restrict__ diag, float* __restrict__ out) {
  int c = threadIdx.x;
  float v = (c < K_C) ? sqrtf(diag[c] + 1e-15f) : 0.f;
#pragma unroll
  for (int off = 8; off; off >>= 1) v += __shfl_xor(v, off, 16);
  if (c == 0) out[0] = -v / sqrtf((float)N_NODES * (float)K_C);
}

extern "C" void kernel_launch(void* const* d_in, const int* in_sizes, int n_in,
                              void* d_out, int out_size, void* d_ws, size_t ws_size,
                              hipStream_t stream) {
  const float* x  = (const float*)d_in[0];
  const int*   ei = (const int*)d_in[1];
  const float* ew = (const float*)d_in[2];
  const float* W1 = (const float*)d_in[3];
  const float* b1 = (const float*)d_in[4];
  const float* W2 = (const float*)d_in[5];
  const float* b2 = (const float*)d_in[6];
  const float* Wm = (const float*)d_in[7];
  const float* bm = (const float*)d_in[8];
  float* out = (float*)d_out;

  const int* srcv = ei;
  const int* dstv = ei + E_EDGES;

  char* ws = (char*)d_ws;
  float* diag   = (float*)ws;                         // 16 floats
  int*   bsum   = (int*)(ws + 256);                   // 64 ints
  int*   off    = (int*)(ws + 512);                   // N+1 ints
  int*   cursor = off + (N_NODES + 64);               // N ints (also deg)
  int2*  csr    = (int2*)(cursor + N_NODES);          // E int2 = 6.4 MB
  float* bufA   = (float*)((char*)(csr + E_EDGES));   // N*64 fp32 region (12.8 MB)
  float* bufB   = bufA + (size_t)N_NODES * IN_F;      // N*128 fp32 region (25.6 MB)

  __half* xh  = (__half*)bufB;   // fp16 x (6.4 MB), dead after gather_x
  __half* t2h = (__half*)bufA;   // fp16 t2 (12.8 MB), written after agg_x is dead
  __half* h2h = (__half*)bufB;   // fp16 h2 (12.8 MB), written after h1 is dead

  hipMemsetAsync(diag, 0, K_C * sizeof(float), stream);
  hipMemsetAsync(cursor, 0, N_NODES * sizeof(int), stream);

  // CSR build
  hist_kernel<<<(E_EDGES + 255) / 256, 256, 0, stream>>>(dstv, cursor);
  scan_local<<<NB, SCAN_B, 0, stream>>>(cursor, off, bsum);
  scan_block<<<1, 64, 0, stream>>>(bsum);
  add_base<<<NB, SCAN_B, 0, stream>>>(off, bsum, cursor);
  fill_kernel<<<(E_EDGES + 255) / 256, 256, 0, stream>>>(srcv, dstv, ew, cursor, csr);

  // layer 1 (reordered): xh = fp16(x); aggx = A*xh; h1 = relu(aggx @ W1 + b1)
  f2h_kernel<<<(N_NODES * IN_F / 4 + 255) / 256, 256, 0, stream>>>(x, xh, N_NODES * IN_F / 4);
  gather_x<<<N_NODES / 4, 256, 0, stream>>>(xh, off, csr, bufA);
  gemm_rows<IN_F, true, float><<<(N_NODES + 31) / 32, 256, 0, stream>>>(bufA, W1, b1, bufB, N_NODES);

  // layer 2: t2h = fp16(h1 @ W2); h2h = fp16(A * t2h)
  gemm_rows<H_F, false, __half><<<(N_NODES + 31) / 32, 256, 0, stream>>>(bufB, W2, nullptr, t2h, N_NODES);
  gather_h<<<N_NODES / 4, 256, 0, stream>>>(t2h, off, csr, h2h);

  // head
  head_kernel<<<(N_NODES + 15) / 16, 256, 0, stream>>>(h2h, b2, Wm, bm, out, diag, N_NODES);
  loss_kernel<<<1, 64, 0, stream>>>(diag, out + (size_t)N_NODES * K_C);
}

// Round 7
// 266.648 us; speedup vs baseline: 11.2605x; 1.1084x over previous
//
#include <hip/hip_runtime.h>
#include <hip/hip_fp16.h>
#include <math.h>
#include <type_traits>

static constexpr int N_NODES = 50000;
static constexpr int E_EDGES = 800000;
static constexpr int IN_F = 64;
static constexpr int H_F = 128;
static constexpr int K_C = 16;
static constexpr int SCAN_B = 1024;
static constexpr int NB = (N_NODES + SCAN_B - 1) / SCAN_B;   // 49

// ---------------- CSR build (counting sort by dst) ----------------
// CSR entry: packed uint = src (low 16) | fp16 weight bits (high 16).

__global__ __launch_bounds__(256) void hist_kernel(
    const int* __restrict__ dst, int* __restrict__ deg) {
  int e = blockIdx.x * 256 + threadIdx.x;
  if (e < E_EDGES) atomicAdd(&deg[dst[e]], 1);
}

__global__ __launch_bounds__(1024) void scan_local(
    const int* __restrict__ deg, int* __restrict__ off, int* __restrict__ blockSum) {
  __shared__ int part[SCAN_B];
  const int tid = threadIdx.x;
  const int i = blockIdx.x * SCAN_B + tid;
  const int v = (i < N_NODES) ? deg[i] : 0;
  part[tid] = v;
  __syncthreads();
  for (int d = 1; d < SCAN_B; d <<= 1) {
    int add = (tid >= d) ? part[tid - d] : 0;
    __syncthreads();
    part[tid] += add;
    __syncthreads();
  }
  if (i < N_NODES) off[i] = part[tid] - v;           // exclusive, block-local
  if (tid == SCAN_B - 1) blockSum[blockIdx.x] = part[tid];
}

__global__ __launch_bounds__(64) void scan_block(int* __restrict__ blockSum) {
  const int t = threadIdx.x;
  int v = (t < NB) ? blockSum[t] : 0;
  int inc = v;
#pragma unroll
  for (int d = 1; d < 64; d <<= 1) {
    int u = __shfl_up(inc, d);
    if (t >= d) inc += u;
  }
  if (t < NB) blockSum[t] = inc - v;                 // exclusive base
}

__global__ __launch_bounds__(1024) void add_base(
    int* __restrict__ off, const int* __restrict__ blockSum, int* __restrict__ cursor) {
  const int i = blockIdx.x * SCAN_B + threadIdx.x;
  if (i < N_NODES) {
    int o = off[i] + blockSum[blockIdx.x];
    off[i] = o;
    cursor[i] = o;
  }
  if (i == 0) off[N_NODES] = E_EDGES;
}

__global__ __launch_bounds__(256) void fill_kernel(
    const int* __restrict__ src, const int* __restrict__ dst,
    const float* __restrict__ w, int* __restrict__ cursor,
    unsigned int* __restrict__ csr) {
  int e = blockIdx.x * 256 + threadIdx.x;
  if (e >= E_EDGES) return;
  int d = dst[e];
  int pos = atomicAdd(&cursor[d], 1);
  const unsigned short wb = __half_as_ushort(__float2half_rn(w[e]));
  csr[pos] = (unsigned int)src[e] | ((unsigned int)wb << 16);
}

__device__ __forceinline__ void unpack(unsigned int e, int& s, float& w) {
  s = (int)(e & 0xffffu);
  w = __half2float(__ushort_as_half((unsigned short)(e >> 16)));
}

// ---------------- fp32 -> fp16 conversion (4 elems/thread) ----------------
__global__ __launch_bounds__(256) void f2h_kernel(
    const float* __restrict__ in, __half* __restrict__ out, int n4) {
  int i = blockIdx.x * 256 + threadIdx.x;
  if (i >= n4) return;
  float4 v = ((const float4*)in)[i];
  __half2* o = (__half2*)out + (size_t)i * 2;
  o[0] = __floats2half2_rn(v.x, v.y);
  o[1] = __floats2half2_rn(v.z, v.w);
}

// ---------------- gather aggregation ----------------
// Layer-1 pre-aggregation over fp16 x: 64 feats, 1 half/lane, 8-way unroll.
__global__ __launch_bounds__(256) void gather_x(
    const __half* __restrict__ t, const int* __restrict__ off,
    const unsigned int* __restrict__ csr, float* __restrict__ outb) {
  const int node = blockIdx.x * 4 + (threadIdx.x >> 6);
  const int lane = threadIdx.x & 63;
  const int p0 = off[node], p1 = off[node + 1];
  float a0 = 0.f, a1 = 0.f, a2 = 0.f, a3 = 0.f;
  int p = p0;
  for (; p + 8 <= p1; p += 8) {
    int s0, s1, s2, s3, s4, s5, s6, s7;
    float w0, w1, w2, w3, w4, w5, w6, w7;
    unpack(csr[p], s0, w0);     unpack(csr[p + 1], s1, w1);
    unpack(csr[p + 2], s2, w2); unpack(csr[p + 3], s3, w3);
    unpack(csr[p + 4], s4, w4); unpack(csr[p + 5], s5, w5);
    unpack(csr[p + 6], s6, w6); unpack(csr[p + 7], s7, w7);
    const float v0 = __half2float(t[(size_t)s0 * IN_F + lane]);
    const float v1 = __half2float(t[(size_t)s1 * IN_F + lane]);
    const float v2 = __half2float(t[(size_t)s2 * IN_F + lane]);
    const float v3 = __half2float(t[(size_t)s3 * IN_F + lane]);
    const float v4 = __half2float(t[(size_t)s4 * IN_F + lane]);
    const float v5 = __half2float(t[(size_t)s5 * IN_F + lane]);
    const float v6 = __half2float(t[(size_t)s6 * IN_F + lane]);
    const float v7 = __half2float(t[(size_t)s7 * IN_F + lane]);
    a0 = fmaf(v0, w0, a0); a1 = fmaf(v1, w1, a1);
    a2 = fmaf(v2, w2, a2); a3 = fmaf(v3, w3, a3);
    a0 = fmaf(v4, w4, a0); a1 = fmaf(v5, w5, a1);
    a2 = fmaf(v6, w6, a2); a3 = fmaf(v7, w7, a3);
  }
  for (; p < p1; ++p) {
    int s; float w;
    unpack(csr[p], s, w);
    a0 = fmaf(__half2float(t[(size_t)s * IN_F + lane]), w, a0);
  }
  outb[(size_t)node * IN_F + lane] = (a0 + a1) + (a2 + a3);
}

// Layer-2 aggregation over fp16 t2: 128 feats, half2/lane, 8-way unroll; fp16 out.
__global__ __launch_bounds__(256) void gather_h(
    const __half* __restrict__ t, const int* __restrict__ off,
    const unsigned int* __restrict__ csr, __half* __restrict__ outb) {
  const int node = blockIdx.x * 4 + (threadIdx.x >> 6);
  const int lane = threadIdx.x & 63;
  const __half2* __restrict__ tb = (const __half2*)t;
  const int p0 = off[node], p1 = off[node + 1];
  float2 a0 = make_float2(0.f, 0.f), a1 = make_float2(0.f, 0.f);
  float2 a2 = make_float2(0.f, 0.f), a3 = make_float2(0.f, 0.f);
  int p = p0;
  for (; p + 8 <= p1; p += 8) {
    int s0, s1, s2, s3, s4, s5, s6, s7;
    float w0, w1, w2, w3, w4, w5, w6, w7;
    unpack(csr[p], s0, w0);     unpack(csr[p + 1], s1, w1);
    unpack(csr[p + 2], s2, w2); unpack(csr[p + 3], s3, w3);
    unpack(csr[p + 4], s4, w4); unpack(csr[p + 5], s5, w5);
    unpack(csr[p + 6], s6, w6); unpack(csr[p + 7], s7, w7);
    const __half2 h0 = tb[(size_t)s0 * 64 + lane];
    const __half2 h1 = tb[(size_t)s1 * 64 + lane];
    const __half2 h2 = tb[(size_t)s2 * 64 + lane];
    const __half2 h3 = tb[(size_t)s3 * 64 + lane];
    const __half2 h4 = tb[(size_t)s4 * 64 + lane];
    const __half2 h5 = tb[(size_t)s5 * 64 + lane];
    const __half2 h6 = tb[(size_t)s6 * 64 + lane];
    const __half2 h7 = tb[(size_t)s7 * 64 + lane];
    float2 f;
    f = __half22float2(h0); a0.x = fmaf(f.x, w0, a0.x); a0.y = fmaf(f.y, w0, a0.y);
    f = __half22float2(h1); a1.x = fmaf(f.x, w1, a1.x); a1.y = fmaf(f.y, w1, a1.y);
    f = __half22float2(h2); a2.x = fmaf(f.x, w2, a2.x); a2.y = fmaf(f.y, w2, a2.y);
    f = __half22float2(h3); a3.x = fmaf(f.x, w3, a3.x); a3.y = fmaf(f.y, w3, a3.y);
    f = __half22float2(h4); a0.x = fmaf(f.x, w4, a0.x); a0.y = fmaf(f.y, w4, a0.y);
    f = __half22float2(h5); a1.x = fmaf(f.x, w5, a1.x); a1.y = fmaf(f.y, w5, a1.y);
    f = __half22float2(h6); a2.x = fmaf(f.x, w6, a2.x); a2.y = fmaf(f.y, w6, a2.y);
    f = __half22float2(h7); a3.x = fmaf(f.x, w7, a3.x); a3.y = fmaf(f.y, w7, a3.y);
  }
  for (; p < p1; ++p) {
    int s; float w;
    unpack(csr[p], s, w);
    const float2 f = __half22float2(tb[(size_t)s * 64 + lane]);
    a0.x = fmaf(f.x, w, a0.x); a0.y = fmaf(f.y, w, a0.y);
  }
  const float2 s = make_float2((a0.x + a1.x) + (a2.x + a3.x),
                               (a0.y + a1.y) + (a2.y + a3.y));
  ((__half2*)outb)[(size_t)node * 64 + lane] = __float22half2_rn(s);
}

// ---------------- dense transform ----------------
template<int KIN, bool BIAS_RELU, typename OutT>
__global__ __launch_bounds__(256) void gemm_rows(
    const float* __restrict__ in, const float* __restrict__ W,
    const float* __restrict__ bias, OutT* __restrict__ out, int n) {
  constexpr int ROWS = 32;
  __shared__ float Xs[ROWS * KIN];
  const int i0 = blockIdx.x * ROWS;
  const int nrow = (n - i0 < ROWS) ? (n - i0) : ROWS;
  for (int t = threadIdx.x; t < nrow * (KIN / 4); t += 256)
    ((float4*)Xs)[t] = ((const float4*)(in + (size_t)i0 * KIN))[t];
  __syncthreads();

  const int j = threadIdx.x & 127;
  const int rg = (threadIdx.x >> 7) * 16;
  float acc[16];
#pragma unroll
  for (int r = 0; r < 16; ++r) acc[r] = 0.f;

  for (int k4 = 0; k4 < KIN / 4; ++k4) {
    const int k = k4 * 4;
    float4 wv;
    wv.x = W[(k + 0) * H_F + j];
    wv.y = W[(k + 1) * H_F + j];
    wv.z = W[(k + 2) * H_F + j];
    wv.w = W[(k + 3) * H_F + j];
#pragma unroll
    for (int r = 0; r < 16; ++r) {
      const float4 xv = *(const float4*)(Xs + (rg + r) * KIN + k);  // wave-uniform
      acc[r] = fmaf(xv.x, wv.x, acc[r]);
      acc[r] = fmaf(xv.y, wv.y, acc[r]);
      acc[r] = fmaf(xv.z, wv.z, acc[r]);
      acc[r] = fmaf(xv.w, wv.w, acc[r]);
    }
  }
  const float b = BIAS_RELU ? bias[j] : 0.f;
#pragma unroll
  for (int r = 0; r < 16; ++r) {
    const int i = i0 + rg + r;
    float v = acc[r];
    if (BIAS_RELU) v = fmaxf(v + b, 0.f);
    if (i < n) {
      if constexpr (std::is_same<OutT, __half>::value)
        out[(size_t)i * H_F + j] = __float2half_rn(v);
      else
        out[(size_t)i * H_F + j] = v;
    }
  }
}

// ---------------- head: one node per thread, 16 independent accumulators ----------------
__global__ __launch_bounds__(256) void head_kernel(
    const __half* __restrict__ h2raw, const float* __restrict__ b2,
    const float* __restrict__ Wm, const float* __restrict__ bm,
    float* __restrict__ sm_out, float* __restrict__ diag, int n) {
  __shared__ float Wl[H_F * K_C];   // 8 KB, [k][c]
  __shared__ float b2l[H_F];
  __shared__ float part[K_C];
  for (int t = threadIdx.x; t < H_F * K_C; t += 256) Wl[t] = Wm[t];
  if (threadIdx.x < H_F) b2l[threadIdx.x] = b2[threadIdx.x];
  if (threadIdx.x < K_C) part[threadIdx.x] = 0.f;
  __syncthreads();

  const int node = blockIdx.x * 256 + threadIdx.x;
  const int lane = threadIdx.x & 63;
  float acc[K_C];
#pragma unroll
  for (int c = 0; c < K_C; ++c) acc[c] = bm[c];

  if (node < n) {
    const __half2* __restrict__ hrow = (const __half2*)(h2raw + (size_t)node * H_F);
#pragma unroll 4
    for (int k2 = 0; k2 < H_F / 2; ++k2) {
      const float2 hv = __half22float2(hrow[k2]);
      const float h0 = fmaxf(hv.x + b2l[2 * k2], 0.f);
      const float h1 = fmaxf(hv.y + b2l[2 * k2 + 1], 0.f);
      const float4* __restrict__ w0 = (const float4*)(Wl + (2 * k2) * K_C);      // uniform
      const float4* __restrict__ w1 = (const float4*)(Wl + (2 * k2 + 1) * K_C);  // uniform
#pragma unroll
      for (int q = 0; q < 4; ++q) {
        const float4 a = w0[q], b = w1[q];
        acc[4 * q + 0] = fmaf(h0, a.x, acc[4 * q + 0]);
        acc[4 * q + 1] = fmaf(h0, a.y, acc[4 * q + 1]);
        acc[4 * q + 2] = fmaf(h0, a.z, acc[4 * q + 2]);
        acc[4 * q + 3] = fmaf(h0, a.w, acc[4 * q + 3]);
        acc[4 * q + 0] = fmaf(h1, b.x, acc[4 * q + 0]);
        acc[4 * q + 1] = fmaf(h1, b.y, acc[4 * q + 1]);
        acc[4 * q + 2] = fmaf(h1, b.z, acc[4 * q + 2]);
        acc[4 * q + 3] = fmaf(h1, b.w, acc[4 * q + 3]);
      }
    }
  }

  // per-thread softmax over 16 registers
  float mx = acc[0];
#pragma unroll
  for (int c = 1; c < K_C; ++c) mx = fmaxf(mx, acc[c]);
  float sum = 0.f;
#pragma unroll
  for (int c = 0; c < K_C; ++c) { acc[c] = __expf(acc[c] - mx); sum += acc[c]; }
  const float inv = 1.f / sum;
  float sq[K_C];
  if (node < n) {
#pragma unroll
    for (int c = 0; c < K_C; ++c) { acc[c] *= inv; sq[c] = acc[c] * acc[c]; }
    float4* o = (float4*)(sm_out + (size_t)node * K_C);
    o[0] = make_float4(acc[0], acc[1], acc[2], acc[3]);
    o[1] = make_float4(acc[4], acc[5], acc[6], acc[7]);
    o[2] = make_float4(acc[8], acc[9], acc[10], acc[11]);
    o[3] = make_float4(acc[12], acc[13], acc[14], acc[15]);
  } else {
#pragma unroll
    for (int c = 0; c < K_C; ++c) sq[c] = 0.f;
  }

  // 64-lane butterfly reduce each of the 16 sq sums; lane 0 -> LDS partials
#pragma unroll
  for (int c = 0; c < K_C; ++c) {
    float v = sq[c];
#pragma unroll
    for (int off = 32; off; off >>= 1) v += __shfl_xor(v, off);
    if (lane == 0) atomicAdd(&part[c], v);
  }
  __syncthreads();
  if (threadIdx.x < K_C) atomicAdd(&diag[threadIdx.x], part[threadIdx.x]);
}

__global__ void loss_kernel(const float* __restrict__ diag, float* __restrict__ out) {
  int c = threadIdx.x;
  float v = (c < K_C) ? sqrtf(diag[c] + 1e-15f) : 0.f;
#pragma unroll
  for (int off = 8; off; off >>= 1) v += __shfl_xor(v, off, 16);
  if (c == 0) out[0] = -v / sqrtf((float)N_NODES * (float)K_C);
}

extern "C" void kernel_launch(void* const* d_in, const int* in_sizes, int n_in,
                              void* d_out, int out_size, void* d_ws, size_t ws_size,
                              hipStream_t stream) {
  const float* x  = (const float*)d_in[0];
  const int*   ei = (const int*)d_in[1];
  const float* ew = (const float*)d_in[2];
  const float* W1 = (const float*)d_in[3];
  const float* b1 = (const float*)d_in[4];
  const float* W2 = (const float*)d_in[5];
  const float* b2 = (const float*)d_in[6];
  const float* Wm = (const float*)d_in[7];
  const float* bm = (const float*)d_in[8];
  float* out = (float*)d_out;

  const int* srcv = ei;
  const int* dstv = ei + E_EDGES;

  char* ws = (char*)d_ws;
  float*        diag   = (float*)ws;                       // 16 floats
  int*          bsum   = (int*)(ws + 256);                 // 64 ints
  int*          off    = (int*)(ws + 512);                 // N+1 ints
  int*          cursor = off + (N_NODES + 64);             // N ints (also deg)
  unsigned int* csr    = (unsigned int*)(cursor + N_NODES);// E uints = 3.2 MB
  float*        bufA   = (float*)(csr + E_EDGES);          // N*64 fp32 (12.8 MB)
  float*        bufB   = bufA + (size_t)N_NODES * IN_F;    // N*128 fp32 (25.6 MB)

  __half* xh  = (__half*)bufB;   // fp16 x (6.4 MB), dead after gather_x
  __half* t2h = (__half*)bufA;   // fp16 t2 (12.8 MB), written after aggx is dead
  __half* h2h = (__half*)bufB;   // fp16 h2 (12.8 MB), written after h1 is dead

  hipMemsetAsync(diag, 0, K_C * sizeof(float), stream);
  hipMemsetAsync(cursor, 0, N_NODES * sizeof(int), stream);

  // CSR build
  hist_kernel<<<(E_EDGES + 255) / 256, 256, 0, stream>>>(dstv, cursor);
  scan_local<<<NB, SCAN_B, 0, stream>>>(cursor, off, bsum);
  scan_block<<<1, 64, 0, stream>>>(bsum);
  add_base<<<NB, SCAN_B, 0, stream>>>(off, bsum, cursor);
  fill_kernel<<<(E_EDGES + 255) / 256, 256, 0, stream>>>(srcv, dstv, ew, cursor, csr);

  // layer 1 (reordered): xh = fp16(x); aggx = A*xh; h1 = relu(aggx @ W1 + b1)
  f2h_kernel<<<(N_NODES * IN_F / 4 + 255) / 256, 256, 0, stream>>>(x, xh, N_NODES * IN_F / 4);
  gather_x<<<N_NODES / 4, 256, 0, stream>>>(xh, off, csr, bufA);
  gemm_rows<IN_F, true, float><<<(N_NODES + 31) / 32, 256, 0, stream>>>(bufA, W1, b1, bufB, N_NODES);

  // layer 2: t2h = fp16(h1 @ W2); h2h = fp16(A * t2h)
  gemm_rows<H_F, false, __half><<<(N_NODES + 31) / 32, 256, 0, stream>>>(bufB, W2, nullptr, t2h, N_NODES);
  gather_h<<<N_NODES / 4, 256, 0, stream>>>(t2h, off, csr, h2h);

  // head
  head_kernel<<<(N_NODES + 255) / 256, 256, 0, stream>>>(h2h, b2, Wm, bm, out, diag, N_NODES);
  loss_kernel<<<1, 64, 0, stream>>>(diag, out + (size_t)N_NODES * K_C);
}

// Round 8
// 233.956 us; speedup vs baseline: 12.8341x; 1.1397x over previous
//
#include <hip/hip_runtime.h>
#include <hip/hip_fp16.h>
#include <math.h>
#include <type_traits>

static constexpr int N_NODES = 50000;
static constexpr int E_EDGES = 800000;
static constexpr int IN_F = 64;
static constexpr int H_F = 128;
static constexpr int K_C = 16;
static constexpr int SCAN_B = 1024;
static constexpr int NB = (N_NODES + SCAN_B - 1) / SCAN_B;   // 49
static constexpr int BUCK_SHIFT = 7;                          // 128 nodes/bucket
static constexpr int NBUCK = (N_NODES + 127) >> BUCK_SHIFT;   // 391
static constexpr int CHUNK_E = 4096;
static constexpr int NCHUNK = (E_EDGES + CHUNK_E - 1) / CHUNK_E; // 196
static constexpr int BUCK_CAP = 4096;

// ---------------- CSR build (two-level counting sort by dst) ----------------
// Final CSR entry: packed uint = src (low 16) | fp16 weight bits (high 16).

__global__ __launch_bounds__(256) void hist_kernel(
    const int* __restrict__ dst, int* __restrict__ deg) {
  int e = blockIdx.x * 256 + threadIdx.x;
  if (e < E_EDGES) atomicAdd(&deg[dst[e]], 1);
}

__global__ __launch_bounds__(1024) void scan_local(
    const int* __restrict__ deg, int* __restrict__ off, int* __restrict__ blockSum) {
  __shared__ int part[SCAN_B];
  const int tid = threadIdx.x;
  const int i = blockIdx.x * SCAN_B + tid;
  const int v = (i < N_NODES) ? deg[i] : 0;
  part[tid] = v;
  __syncthreads();
  for (int d = 1; d < SCAN_B; d <<= 1) {
    int add = (tid >= d) ? part[tid - d] : 0;
    __syncthreads();
    part[tid] += add;
    __syncthreads();
  }
  if (i < N_NODES) off[i] = part[tid] - v;           // exclusive, block-local
  if (tid == SCAN_B - 1) blockSum[blockIdx.x] = part[tid];
}

__global__ __launch_bounds__(64) void scan_block(int* __restrict__ blockSum) {
  const int t = threadIdx.x;
  int v = (t < NB) ? blockSum[t] : 0;
  int inc = v;
#pragma unroll
  for (int d = 1; d < 64; d <<= 1) {
    int u = __shfl_up(inc, d);
    if (t >= d) inc += u;
  }
  if (t < NB) blockSum[t] = inc - v;                 // exclusive base
}

// Adds block base into off; seeds per-bucket global cursors; off[N]=E.
__global__ __launch_bounds__(1024) void add_base(
    int* __restrict__ off, const int* __restrict__ blockSum, int* __restrict__ bcursor) {
  const int i = blockIdx.x * SCAN_B + threadIdx.x;
  if (i < N_NODES) {
    int o = off[i] + blockSum[blockIdx.x];
    off[i] = o;
    if ((i & 127) == 0) bcursor[i >> BUCK_SHIFT] = o;
  }
  if (i == 0) off[N_NODES] = E_EDGES;
}

// Pass 1: LDS counting-sort a 4096-edge chunk by coarse bucket (dst>>7),
// then copy bucket-runs to intermediate at atomically reserved ranges.
// Intermediate entry: .x = src | (dst&127)<<16 | bucket<<23 ... bucket needs
// 9 bits -> store in .y high half: .y = wbits | (bucket<<16).
__global__ __launch_bounds__(256) void bin_pass(
    const int* __restrict__ src, const int* __restrict__ dst,
    const float* __restrict__ w, int* __restrict__ bcursor,
    int2* __restrict__ inter) {
  __shared__ int lhist[NBUCK];   // counts, then running cursors
  __shared__ int lstart[NBUCK];  // local exclusive scan
  __shared__ int bbase[NBUCK];   // reserved global base per bucket
  __shared__ int2 stage[CHUNK_E];  // 32 KB
  const int e0 = blockIdx.x * CHUNK_E;
  const int cnt = min(CHUNK_E, E_EDGES - e0);

  for (int i = threadIdx.x; i < NBUCK; i += 256) lhist[i] = 0;
  __syncthreads();
  for (int i = threadIdx.x; i < cnt; i += 256)
    atomicAdd(&lhist[dst[e0 + i] >> BUCK_SHIFT], 1);
  __syncthreads();

  // one-wave exclusive scan of lhist -> lstart (chunks of 64 with carry)
  if (threadIdx.x < 64) {
    const int lane = threadIdx.x;
    int carry = 0;
    for (int base = 0; base < NBUCK; base += 64) {
      const int idx = base + lane;
      const int v = (idx < NBUCK) ? lhist[idx] : 0;
      int inc = v;
#pragma unroll
      for (int d = 1; d < 64; d <<= 1) {
        int u = __shfl_up(inc, d);
        if (lane >= d) inc += u;
      }
      if (idx < NBUCK) lstart[idx] = carry + inc - v;
      carry += __shfl(inc, 63);
    }
  }
  __syncthreads();

  // reserve global ranges; convert lhist to running local cursors
  for (int b = threadIdx.x; b < NBUCK; b += 256) {
    const int c = lhist[b];
    bbase[b] = (c > 0) ? atomicAdd(&bcursor[b], c) : 0;
    lhist[b] = lstart[b];
  }
  __syncthreads();

  // scatter chunk into LDS, bucket-sorted
  for (int i = threadIdx.x; i < cnt; i += 256) {
    const int d = dst[e0 + i];
    const int b = d >> BUCK_SHIFT;
    const int pos = atomicAdd(&lhist[b], 1);
    const unsigned short wb = __half_as_ushort(__float2half_rn(w[e0 + i]));
    stage[pos] = make_int2(src[e0 + i] | ((d & 127) << 16),
                           (int)wb | (b << 16));
  }
  __syncthreads();

  // copy runs to global (consecutive i within a bucket -> consecutive gpos)
  for (int i = threadIdx.x; i < cnt; i += 256) {
    const int2 en = stage[i];
    const int b = (en.y >> 16) & 0x1ff;
    inter[bbase[b] + (i - lstart[b])] = en;
  }
}

// Pass 2: per-bucket fine counting sort by dst&127 using node-level off,
// then fully coalesced write of the packed CSR segment.
__global__ __launch_bounds__(256) void sort_pass(
    const int2* __restrict__ inter, const int* __restrict__ off,
    unsigned int* __restrict__ csr) {
  __shared__ int lcur[128];
  __shared__ unsigned int outbuf[BUCK_CAP];  // 16 KB
  const int b = blockIdx.x;
  const int n0 = b << BUCK_SHIFT;
  const int r0 = off[n0];
  const int nend = min(n0 + 128, N_NODES);
  const int r1 = off[nend];
  const int cnt = r1 - r0;
  if (threadIdx.x < 128) {
    const int nn = n0 + threadIdx.x;
    lcur[threadIdx.x] = ((nn < N_NODES) ? off[nn] : r1) - r0;
  }
  __syncthreads();
  for (int i = threadIdx.x; i < cnt; i += 256) {
    const int2 en = inter[r0 + i];
    const int dlo = (en.x >> 16) & 127;
    const int pos = atomicAdd(&lcur[dlo], 1);
    outbuf[pos] = (unsigned int)(en.x & 0xffff) |
                  ((unsigned int)(en.y & 0xffff) << 16);
  }
  __syncthreads();
  for (int i = threadIdx.x; i < cnt; i += 256) csr[r0 + i] = outbuf[i];
}

__device__ __forceinline__ void unpack(unsigned int e, int& s, float& w) {
  s = (int)(e & 0xffffu);
  w = __half2float(__ushort_as_half((unsigned short)(e >> 16)));
}

// ---------------- fp32 -> fp16 conversion (4 elems/thread) ----------------
__global__ __launch_bounds__(256) void f2h_kernel(
    const float* __restrict__ in, __half* __restrict__ out, int n4) {
  int i = blockIdx.x * 256 + threadIdx.x;
  if (i >= n4) return;
  float4 v = ((const float4*)in)[i];
  __half2* o = (__half2*)out + (size_t)i * 2;
  o[0] = __floats2half2_rn(v.x, v.y);
  o[1] = __floats2half2_rn(v.z, v.w);
}

// ---------------- gather aggregation ----------------
__global__ __launch_bounds__(256) void gather_x(
    const __half* __restrict__ t, const int* __restrict__ off,
    const unsigned int* __restrict__ csr, float* __restrict__ outb) {
  const int node = blockIdx.x * 4 + (threadIdx.x >> 6);
  const int lane = threadIdx.x & 63;
  const int p0 = off[node], p1 = off[node + 1];
  float a0 = 0.f, a1 = 0.f, a2 = 0.f, a3 = 0.f;
  int p = p0;
  for (; p + 8 <= p1; p += 8) {
    int s0, s1, s2, s3, s4, s5, s6, s7;
    float w0, w1, w2, w3, w4, w5, w6, w7;
    unpack(csr[p], s0, w0);     unpack(csr[p + 1], s1, w1);
    unpack(csr[p + 2], s2, w2); unpack(csr[p + 3], s3, w3);
    unpack(csr[p + 4], s4, w4); unpack(csr[p + 5], s5, w5);
    unpack(csr[p + 6], s6, w6); unpack(csr[p + 7], s7, w7);
    const float v0 = __half2float(t[(size_t)s0 * IN_F + lane]);
    const float v1 = __half2float(t[(size_t)s1 * IN_F + lane]);
    const float v2 = __half2float(t[(size_t)s2 * IN_F + lane]);
    const float v3 = __half2float(t[(size_t)s3 * IN_F + lane]);
    const float v4 = __half2float(t[(size_t)s4 * IN_F + lane]);
    const float v5 = __half2float(t[(size_t)s5 * IN_F + lane]);
    const float v6 = __half2float(t[(size_t)s6 * IN_F + lane]);
    const float v7 = __half2float(t[(size_t)s7 * IN_F + lane]);
    a0 = fmaf(v0, w0, a0); a1 = fmaf(v1, w1, a1);
    a2 = fmaf(v2, w2, a2); a3 = fmaf(v3, w3, a3);
    a0 = fmaf(v4, w4, a0); a1 = fmaf(v5, w5, a1);
    a2 = fmaf(v6, w6, a2); a3 = fmaf(v7, w7, a3);
  }
  for (; p < p1; ++p) {
    int s; float w;
    unpack(csr[p], s, w);
    a0 = fmaf(__half2float(t[(size_t)s * IN_F + lane]), w, a0);
  }
  outb[(size_t)node * IN_F + lane] = (a0 + a1) + (a2 + a3);
}

__global__ __launch_bounds__(256) void gather_h(
    const __half* __restrict__ t, const int* __restrict__ off,
    const unsigned int* __restrict__ csr, __half* __restrict__ outb) {
  const int node = blockIdx.x * 4 + (threadIdx.x >> 6);
  const int lane = threadIdx.x & 63;
  const __half2* __restrict__ tb = (const __half2*)t;
  const int p0 = off[node], p1 = off[node + 1];
  float2 a0 = make_float2(0.f, 0.f), a1 = make_float2(0.f, 0.f);
  float2 a2 = make_float2(0.f, 0.f), a3 = make_float2(0.f, 0.f);
  int p = p0;
  for (; p + 8 <= p1; p += 8) {
    int s0, s1, s2, s3, s4, s5, s6, s7;
    float w0, w1, w2, w3, w4, w5, w6, w7;
    unpack(csr[p], s0, w0);     unpack(csr[p + 1], s1, w1);
    unpack(csr[p + 2], s2, w2); unpack(csr[p + 3], s3, w3);
    unpack(csr[p + 4], s4, w4); unpack(csr[p + 5], s5, w5);
    unpack(csr[p + 6], s6, w6); unpack(csr[p + 7], s7, w7);
    const __half2 h0 = tb[(size_t)s0 * 64 + lane];
    const __half2 h1 = tb[(size_t)s1 * 64 + lane];
    const __half2 h2 = tb[(size_t)s2 * 64 + lane];
    const __half2 h3 = tb[(size_t)s3 * 64 + lane];
    const __half2 h4 = tb[(size_t)s4 * 64 + lane];
    const __half2 h5 = tb[(size_t)s5 * 64 + lane];
    const __half2 h6 = tb[(size_t)s6 * 64 + lane];
    const __half2 h7 = tb[(size_t)s7 * 64 + lane];
    float2 f;
    f = __half22float2(h0); a0.x = fmaf(f.x, w0, a0.x); a0.y = fmaf(f.y, w0, a0.y);
    f = __half22float2(h1); a1.x = fmaf(f.x, w1, a1.x); a1.y = fmaf(f.y, w1, a1.y);
    f = __half22float2(h2); a2.x = fmaf(f.x, w2, a2.x); a2.y = fmaf(f.y, w2, a2.y);
    f = __half22float2(h3); a3.x = fmaf(f.x, w3, a3.x); a3.y = fmaf(f.y, w3, a3.y);
    f = __half22float2(h4); a0.x = fmaf(f.x, w4, a0.x); a0.y = fmaf(f.y, w4, a0.y);
    f = __half22float2(h5); a1.x = fmaf(f.x, w5, a1.x); a1.y = fmaf(f.y, w5, a1.y);
    f = __half22float2(h6); a2.x = fmaf(f.x, w6, a2.x); a2.y = fmaf(f.y, w6, a2.y);
    f = __half22float2(h7); a3.x = fmaf(f.x, w7, a3.x); a3.y = fmaf(f.y, w7, a3.y);
  }
  for (; p < p1; ++p) {
    int s; float w;
    unpack(csr[p], s, w);
    const float2 f = __half22float2(tb[(size_t)s * 64 + lane]);
    a0.x = fmaf(f.x, w, a0.x); a0.y = fmaf(f.y, w, a0.y);
  }
  const float2 s = make_float2((a0.x + a1.x) + (a2.x + a3.x),
                               (a0.y + a1.y) + (a2.y + a3.y));
  ((__half2*)outb)[(size_t)node * 64 + lane] = __float22half2_rn(s);
}

// ---------------- dense transform ----------------
template<int KIN, bool BIAS_RELU, typename OutT>
__global__ __launch_bounds__(256) void gemm_rows(
    const float* __restrict__ in, const float* __restrict__ W,
    const float* __restrict__ bias, OutT* __restrict__ out, int n) {
  constexpr int ROWS = 32;
  __shared__ float Xs[ROWS * KIN];
  const int i0 = blockIdx.x * ROWS;
  const int nrow = (n - i0 < ROWS) ? (n - i0) : ROWS;
  for (int t = threadIdx.x; t < nrow * (KIN / 4); t += 256)
    ((float4*)Xs)[t] = ((const float4*)(in + (size_t)i0 * KIN))[t];
  __syncthreads();

  const int j = threadIdx.x & 127;
  const int rg = (threadIdx.x >> 7) * 16;
  float acc[16];
#pragma unroll
  for (int r = 0; r < 16; ++r) acc[r] = 0.f;

  for (int k4 = 0; k4 < KIN / 4; ++k4) {
    const int k = k4 * 4;
    float4 wv;
    wv.x = W[(k + 0) * H_F + j];
    wv.y = W[(k + 1) * H_F + j];
    wv.z = W[(k + 2) * H_F + j];
    wv.w = W[(k + 3) * H_F + j];
#pragma unroll
    for (int r = 0; r < 16; ++r) {
      const float4 xv = *(const float4*)(Xs + (rg + r) * KIN + k);  // wave-uniform
      acc[r] = fmaf(xv.x, wv.x, acc[r]);
      acc[r] = fmaf(xv.y, wv.y, acc[r]);
      acc[r] = fmaf(xv.z, wv.z, acc[r]);
      acc[r] = fmaf(xv.w, wv.w, acc[r]);
    }
  }
  const float b = BIAS_RELU ? bias[j] : 0.f;
#pragma unroll
  for (int r = 0; r < 16; ++r) {
    const int i = i0 + rg + r;
    float v = acc[r];
    if (BIAS_RELU) v = fmaxf(v + b, 0.f);
    if (i < n) {
      if constexpr (std::is_same<OutT, __half>::value)
        out[(size_t)i * H_F + j] = __float2half_rn(v);
      else
        out[(size_t)i * H_F + j] = v;
    }
  }
}

// ---------------- head: one node per thread, 16 independent accumulators ----------------
__global__ __launch_bounds__(256) void head_kernel(
    const __half* __restrict__ h2raw, const float* __restrict__ b2,
    const float* __restrict__ Wm, const float* __restrict__ bm,
    float* __restrict__ sm_out, float* __restrict__ diag, int n) {
  __shared__ float Wl[H_F * K_C];   // 8 KB, [k][c]
  __shared__ float b2l[H_F];
  __shared__ float part[K_C];
  for (int t = threadIdx.x; t < H_F * K_C; t += 256) Wl[t] = Wm[t];
  if (threadIdx.x < H_F) b2l[threadIdx.x] = b2[threadIdx.x];
  if (threadIdx.x < K_C) part[threadIdx.x] = 0.f;
  __syncthreads();

  const int node = blockIdx.x * 256 + threadIdx.x;
  const int lane = threadIdx.x & 63;
  float acc[K_C];
#pragma unroll
  for (int c = 0; c < K_C; ++c) acc[c] = bm[c];

  if (node < n) {
    const __half2* __restrict__ hrow = (const __half2*)(h2raw + (size_t)node * H_F);
#pragma unroll 4
    for (int k2 = 0; k2 < H_F / 2; ++k2) {
      const float2 hv = __half22float2(hrow[k2]);
      const float h0 = fmaxf(hv.x + b2l[2 * k2], 0.f);
      const float h1 = fmaxf(hv.y + b2l[2 * k2 + 1], 0.f);
      const float4* __restrict__ w0 = (const float4*)(Wl + (2 * k2) * K_C);      // uniform
      const float4* __restrict__ w1 = (const float4*)(Wl + (2 * k2 + 1) * K_C);  // uniform
#pragma unroll
      for (int q = 0; q < 4; ++q) {
        const float4 a = w0[q], b = w1[q];
        acc[4 * q + 0] = fmaf(h0, a.x, acc[4 * q + 0]);
        acc[4 * q + 1] = fmaf(h0, a.y, acc[4 * q + 1]);
        acc[4 * q + 2] = fmaf(h0, a.z, acc[4 * q + 2]);
        acc[4 * q + 3] = fmaf(h0, a.w, acc[4 * q + 3]);
        acc[4 * q + 0] = fmaf(h1, b.x, acc[4 * q + 0]);
        acc[4 * q + 1] = fmaf(h1, b.y, acc[4 * q + 1]);
        acc[4 * q + 2] = fmaf(h1, b.z, acc[4 * q + 2]);
        acc[4 * q + 3] = fmaf(h1, b.w, acc[4 * q + 3]);
      }
    }
  }

  // per-thread softmax over 16 registers
  float mx = acc[0];
#pragma unroll
  for (int c = 1; c < K_C; ++c) mx = fmaxf(mx, acc[c]);
  float sum = 0.f;
#pragma unroll
  for (int c = 0; c < K_C; ++c) { acc[c] = __expf(acc[c] - mx); sum += acc[c]; }
  const float inv = 1.f / sum;
  float sq[K_C];
  if (node < n) {
#pragma unroll
    for (int c = 0; c < K_C; ++c) { acc[c] *= inv; sq[c] = acc[c] * acc[c]; }
    float4* o = (float4*)(sm_out + (size_t)node * K_C);
    o[0] = make_float4(acc[0], acc[1], acc[2], acc[3]);
    o[1] = make_float4(acc[4], acc[5], acc[6], acc[7]);
    o[2] = make_float4(acc[8], acc[9], acc[10], acc[11]);
    o[3] = make_float4(acc[12], acc[13], acc[14], acc[15]);
  } else {
#pragma unroll
    for (int c = 0; c < K_C; ++c) sq[c] = 0.f;
  }

  // 64-lane butterfly reduce each of the 16 sq sums; lane 0 -> LDS partials
#pragma unroll
  for (int c = 0; c < K_C; ++c) {
    float v = sq[c];
#pragma unroll
    for (int off = 32; off; off >>= 1) v += __shfl_xor(v, off);
    if (lane == 0) atomicAdd(&part[c], v);
  }
  __syncthreads();
  if (threadIdx.x < K_C) atomicAdd(&diag[threadIdx.x], part[threadIdx.x]);
}

__global__ void loss_kernel(const float* __restrict__ diag, float* __restrict__ out) {
  int c = threadIdx.x;
  float v = (c < K_C) ? sqrtf(diag[c] + 1e-15f) : 0.f;
#pragma unroll
  for (int off = 8; off; off >>= 1) v += __shfl_xor(v, off, 16);
  if (c == 0) out[0] = -v / sqrtf((float)N_NODES * (float)K_C);
}

extern "C" void kernel_launch(void* const* d_in, const int* in_sizes, int n_in,
                              void* d_out, int out_size, void* d_ws, size_t ws_size,
                              hipStream_t stream) {
  const float* x  = (const float*)d_in[0];
  const int*   ei = (const int*)d_in[1];
  const float* ew = (const float*)d_in[2];
  const float* W1 = (const float*)d_in[3];
  const float* b1 = (const float*)d_in[4];
  const float* W2 = (const float*)d_in[5];
  const float* b2 = (const float*)d_in[6];
  const float* Wm = (const float*)d_in[7];
  const float* bm = (const float*)d_in[8];
  float* out = (float*)d_out;

  const int* srcv = ei;
  const int* dstv = ei + E_EDGES;

  char* ws = (char*)d_ws;
  float*        diag    = (float*)ws;                        // 16 floats
  int*          bsum    = (int*)(ws + 256);                  // 64 ints
  int*          bcursor = (int*)(ws + 512);                  // NBUCK ints
  int*          off     = (int*)(ws + 4096);                 // N+1 ints
  int*          deg     = off + (N_NODES + 64);              // N ints
  unsigned int* csr     = (unsigned int*)(deg + N_NODES);    // E uints (3.2 MB)
  int2*         inter   = (int2*)(csr + E_EDGES);            // E int2 (6.4 MB)
  float*        bufA    = (float*)(inter + E_EDGES);         // N*64 fp32 (12.8 MB)
  float*        bufB    = bufA + (size_t)N_NODES * IN_F;     // N*128 fp32 (25.6 MB)

  __half* xh  = (__half*)bufB;   // fp16 x (6.4 MB), dead after gather_x
  __half* t2h = (__half*)bufA;   // fp16 t2 (12.8 MB), written after aggx is dead
  __half* h2h = (__half*)bufB;   // fp16 h2 (12.8 MB), written after h1 is dead

  hipMemsetAsync(diag, 0, K_C * sizeof(float), stream);
  hipMemsetAsync(deg, 0, N_NODES * sizeof(int), stream);

  // CSR build: hist -> scan -> two-level counting sort
  hist_kernel<<<(E_EDGES + 255) / 256, 256, 0, stream>>>(dstv, deg);
  scan_local<<<NB, SCAN_B, 0, stream>>>(deg, off, bsum);
  scan_block<<<1, 64, 0, stream>>>(bsum);
  add_base<<<NB, SCAN_B, 0, stream>>>(off, bsum, bcursor);
  bin_pass<<<NCHUNK, 256, 0, stream>>>(srcv, dstv, ew, bcursor, inter);
  sort_pass<<<NBUCK, 256, 0, stream>>>(inter, off, csr);

  // layer 1 (reordered): xh = fp16(x); aggx = A*xh; h1 = relu(aggx @ W1 + b1)
  f2h_kernel<<<(N_NODES * IN_F / 4 + 255) / 256, 256, 0, stream>>>(x, xh, N_NODES * IN_F / 4);
  gather_x<<<N_NODES / 4, 256, 0, stream>>>(xh, off, csr, bufA);
  gemm_rows<IN_F, true, float><<<(N_NODES + 31) / 32, 256, 0, stream>>>(bufA, W1, b1, bufB, N_NODES);

  // layer 2: t2h = fp16(h1 @ W2); h2h = fp16(A * t2h)
  gemm_rows<H_F, false, __half><<<(N_NODES + 31) / 32, 256, 0, stream>>>(bufB, W2, nullptr, t2h, N_NODES);
  gather_h<<<N_NODES / 4, 256, 0, stream>>>(t2h, off, csr, h2h);

  // head
  head_kernel<<<(N_NODES + 255) / 256, 256, 0, stream>>>(h2h, b2, Wm, bm, out, diag, N_NODES);
  loss_kernel<<<1, 64, 0, stream>>>(diag, out + (size_t)N_NODES * K_C);
}

// Round 9
// 196.776 us; speedup vs baseline: 15.2589x; 1.1889x over previous
//
#include <hip/hip_runtime.h>
#include <hip/hip_fp16.h>
#include <math.h>

static constexpr int N_NODES = 50000;
static constexpr int E_EDGES = 800000;
static constexpr int IN_F = 64;
static constexpr int H_F = 128;
static constexpr int K_C = 16;
static constexpr int SCAN_B = 1024;
static constexpr int NB = (N_NODES + SCAN_B - 1) / SCAN_B;   // 49
static constexpr int BUCK_SHIFT = 7;                          // 128 nodes/bucket
static constexpr int NBUCK = (N_NODES + 127) >> BUCK_SHIFT;   // 391
static constexpr int CHUNK_E = 4096;
static constexpr int NCHUNK = (E_EDGES + CHUNK_E - 1) / CHUNK_E; // 196
static constexpr int BUCK_CAP = 4096;

typedef _Float16 h8 __attribute__((ext_vector_type(8)));
typedef float f4 __attribute__((ext_vector_type(4)));

// ---------------- CSR build (two-level counting sort by dst) ----------------

__global__ __launch_bounds__(256) void hist_kernel(
    const int* __restrict__ dst, int* __restrict__ deg) {
  int e = blockIdx.x * 256 + threadIdx.x;
  if (e < E_EDGES) atomicAdd(&deg[dst[e]], 1);
}

__global__ __launch_bounds__(1024) void scan_local(
    const int* __restrict__ deg, int* __restrict__ off, int* __restrict__ blockSum) {
  __shared__ int part[SCAN_B];
  const int tid = threadIdx.x;
  const int i = blockIdx.x * SCAN_B + tid;
  const int v = (i < N_NODES) ? deg[i] : 0;
  part[tid] = v;
  __syncthreads();
  for (int d = 1; d < SCAN_B; d <<= 1) {
    int add = (tid >= d) ? part[tid - d] : 0;
    __syncthreads();
    part[tid] += add;
    __syncthreads();
  }
  if (i < N_NODES) off[i] = part[tid] - v;           // exclusive, block-local
  if (tid == SCAN_B - 1) blockSum[blockIdx.x] = part[tid];
}

__global__ __launch_bounds__(64) void scan_block(int* __restrict__ blockSum) {
  const int t = threadIdx.x;
  int v = (t < NB) ? blockSum[t] : 0;
  int inc = v;
#pragma unroll
  for (int d = 1; d < 64; d <<= 1) {
    int u = __shfl_up(inc, d);
    if (t >= d) inc += u;
  }
  if (t < NB) blockSum[t] = inc - v;                 // exclusive base
}

__global__ __launch_bounds__(1024) void add_base(
    int* __restrict__ off, const int* __restrict__ blockSum, int* __restrict__ bcursor) {
  const int i = blockIdx.x * SCAN_B + threadIdx.x;
  if (i < N_NODES) {
    int o = off[i] + blockSum[blockIdx.x];
    off[i] = o;
    if ((i & 127) == 0) bcursor[i >> BUCK_SHIFT] = o;
  }
  if (i == 0) off[N_NODES] = E_EDGES;
}

__global__ __launch_bounds__(256) void bin_pass(
    const int* __restrict__ src, const int* __restrict__ dst,
    const float* __restrict__ w, int* __restrict__ bcursor,
    int2* __restrict__ inter) {
  __shared__ int lhist[NBUCK];
  __shared__ int lstart[NBUCK];
  __shared__ int bbase[NBUCK];
  __shared__ int2 stage[CHUNK_E];  // 32 KB
  const int e0 = blockIdx.x * CHUNK_E;
  const int cnt = min(CHUNK_E, E_EDGES - e0);

  for (int i = threadIdx.x; i < NBUCK; i += 256) lhist[i] = 0;
  __syncthreads();
  for (int i = threadIdx.x; i < cnt; i += 256)
    atomicAdd(&lhist[dst[e0 + i] >> BUCK_SHIFT], 1);
  __syncthreads();

  if (threadIdx.x < 64) {
    const int lane = threadIdx.x;
    int carry = 0;
    for (int base = 0; base < NBUCK; base += 64) {
      const int idx = base + lane;
      const int v = (idx < NBUCK) ? lhist[idx] : 0;
      int inc = v;
#pragma unroll
      for (int d = 1; d < 64; d <<= 1) {
        int u = __shfl_up(inc, d);
        if (lane >= d) inc += u;
      }
      if (idx < NBUCK) lstart[idx] = carry + inc - v;
      carry += __shfl(inc, 63);
    }
  }
  __syncthreads();

  for (int b = threadIdx.x; b < NBUCK; b += 256) {
    const int c = lhist[b];
    bbase[b] = (c > 0) ? atomicAdd(&bcursor[b], c) : 0;
    lhist[b] = lstart[b];
  }
  __syncthreads();

  for (int i = threadIdx.x; i < cnt; i += 256) {
    const int d = dst[e0 + i];
    const int b = d >> BUCK_SHIFT;
    const int pos = atomicAdd(&lhist[b], 1);
    const unsigned short wb = __half_as_ushort(__float2half_rn(w[e0 + i]));
    stage[pos] = make_int2(src[e0 + i] | ((d & 127) << 16),
                           (int)wb | (b << 16));
  }
  __syncthreads();

  for (int i = threadIdx.x; i < cnt; i += 256) {
    const int2 en = stage[i];
    const int b = (en.y >> 16) & 0x1ff;
    inter[bbase[b] + (i - lstart[b])] = en;
  }
}

__global__ __launch_bounds__(256) void sort_pass(
    const int2* __restrict__ inter, const int* __restrict__ off,
    unsigned int* __restrict__ csr) {
  __shared__ int lcur[128];
  __shared__ unsigned int outbuf[BUCK_CAP];  // 16 KB
  const int b = blockIdx.x;
  const int n0 = b << BUCK_SHIFT;
  const int r0 = off[n0];
  const int nend = min(n0 + 128, N_NODES);
  const int r1 = off[nend];
  const int cnt = r1 - r0;
  if (threadIdx.x < 128) {
    const int nn = n0 + threadIdx.x;
    lcur[threadIdx.x] = ((nn < N_NODES) ? off[nn] : r1) - r0;
  }
  __syncthreads();
  for (int i = threadIdx.x; i < cnt; i += 256) {
    const int2 en = inter[r0 + i];
    const int dlo = (en.x >> 16) & 127;
    const int pos = atomicAdd(&lcur[dlo], 1);
    outbuf[pos] = (unsigned int)(en.x & 0xffff) |
                  ((unsigned int)(en.y & 0xffff) << 16);
  }
  __syncthreads();
  for (int i = threadIdx.x; i < cnt; i += 256) csr[r0 + i] = outbuf[i];
}

__device__ __forceinline__ void unpack(unsigned int e, int& s, float& w) {
  s = (int)(e & 0xffffu);
  w = __half2float(__ushort_as_half((unsigned short)(e >> 16)));
}

// ---------------- fp32 -> fp16 conversion (4 elems/thread) ----------------
__global__ __launch_bounds__(256) void f2h_kernel(
    const float* __restrict__ in, __half* __restrict__ out, int n4) {
  int i = blockIdx.x * 256 + threadIdx.x;
  if (i >= n4) return;
  float4 v = ((const float4*)in)[i];
  __half2* o = (__half2*)out + (size_t)i * 2;
  o[0] = __floats2half2_rn(v.x, v.y);
  o[1] = __floats2half2_rn(v.z, v.w);
}

// ---------------- W transpose + swizzle: W[K][128] fp32 -> WT fp16 ----------------
// WT layout: [col][k] fp16, with byte offset XOR'd by ((col&7)<<4) so that
// per-block LDS staging is a linear copy and ds_read_b128 B-frags are
// 2-way-bank-conflict-free (16B alignment preserved by the XOR).
template<int K>
__global__ __launch_bounds__(256) void transposeW(
    const float* __restrict__ W, __half* __restrict__ WT) {
  int i = blockIdx.x * 256 + threadIdx.x;
  if (i >= K * 128) return;
  const int k = i >> 7, col = i & 127;
  unsigned boff = (unsigned)((col * K + k) * 2);
  boff ^= (unsigned)((col & 7) << 4);
  *(__half*)((char*)WT + boff) = __float2half_rn(W[i]);
}

// ---------------- MFMA dense transform: out[n][128] = A[n][K] @ W ----------------
// 4 waves/block, 64 rows x 128 cols per block; mfma_f32_16x16x32_f16.
template<int K, bool BIAS_RELU>
__global__ __launch_bounds__(256) void gemm_mfma(
    const __half* __restrict__ A, const __half* __restrict__ WT,
    const float* __restrict__ bias, __half* __restrict__ out, int n) {
  __shared__ _Float16 Wl[128 * K];   // K=128: 32 KB, K=64: 16 KB
  for (int t = threadIdx.x; t < 128 * K / 8; t += 256)
    ((uint4*)Wl)[t] = ((const uint4*)WT)[t];
  __syncthreads();

  const int wv = threadIdx.x >> 6;
  const int l = threadIdx.x & 63;
  const int row = l & 15, kg = l >> 4;
  const int r0 = blockIdx.x * 64 + wv * 16;
  const int ar = min(r0 + row, n - 1);    // clamp: garbage stays in discarded C rows

  h8 af[K / 32];
#pragma unroll
  for (int ks = 0; ks < K / 32; ++ks)
    af[ks] = *(const h8*)(A + (size_t)ar * K + ks * 32 + kg * 8);

  const unsigned swz = (unsigned)((row & 7) << 4);   // (c*16+row)&7 == row&7
#pragma unroll
  for (int c = 0; c < 8; ++c) {
    const int col = c * 16 + row;
    f4 acc = {0.f, 0.f, 0.f, 0.f};
#pragma unroll
    for (int ks = 0; ks < K / 32; ++ks) {
      const unsigned boff = ((unsigned)((col * K + ks * 32 + kg * 8) * 2)) ^ swz;
      const h8 bf = *(const h8*)((const char*)Wl + boff);
      acc = __builtin_amdgcn_mfma_f32_16x16x32_f16(af[ks], bf, acc, 0, 0, 0);
    }
    const float bb = BIAS_RELU ? bias[col] : 0.f;
#pragma unroll
    for (int q = 0; q < 4; ++q) {
      const int rr = r0 + kg * 4 + q;
      if (rr < n) {
        float v = acc[q];
        if (BIAS_RELU) v = fmaxf(v + bb, 0.f);
        out[(size_t)rr * H_F + col] = __float2half_rn(v);
      }
    }
  }
}

// ---------------- gather aggregation ----------------
__global__ __launch_bounds__(256) void gather_x(
    const __half* __restrict__ t, const int* __restrict__ off,
    const unsigned int* __restrict__ csr, __half* __restrict__ outb) {
  const int node = blockIdx.x * 4 + (threadIdx.x >> 6);
  const int lane = threadIdx.x & 63;
  const int p0 = off[node], p1 = off[node + 1];
  float a0 = 0.f, a1 = 0.f, a2 = 0.f, a3 = 0.f;
  int p = p0;
  for (; p + 8 <= p1; p += 8) {
    int s0, s1, s2, s3, s4, s5, s6, s7;
    float w0, w1, w2, w3, w4, w5, w6, w7;
    unpack(csr[p], s0, w0);     unpack(csr[p + 1], s1, w1);
    unpack(csr[p + 2], s2, w2); unpack(csr[p + 3], s3, w3);
    unpack(csr[p + 4], s4, w4); unpack(csr[p + 5], s5, w5);
    unpack(csr[p + 6], s6, w6); unpack(csr[p + 7], s7, w7);
    const float v0 = __half2float(t[(size_t)s0 * IN_F + lane]);
    const float v1 = __half2float(t[(size_t)s1 * IN_F + lane]);
    const float v2 = __half2float(t[(size_t)s2 * IN_F + lane]);
    const float v3 = __half2float(t[(size_t)s3 * IN_F + lane]);
    const float v4 = __half2float(t[(size_t)s4 * IN_F + lane]);
    const float v5 = __half2float(t[(size_t)s5 * IN_F + lane]);
    const float v6 = __half2float(t[(size_t)s6 * IN_F + lane]);
    const float v7 = __half2float(t[(size_t)s7 * IN_F + lane]);
    a0 = fmaf(v0, w0, a0); a1 = fmaf(v1, w1, a1);
    a2 = fmaf(v2, w2, a2); a3 = fmaf(v3, w3, a3);
    a0 = fmaf(v4, w4, a0); a1 = fmaf(v5, w5, a1);
    a2 = fmaf(v6, w6, a2); a3 = fmaf(v7, w7, a3);
  }
  for (; p < p1; ++p) {
    int s; float w;
    unpack(csr[p], s, w);
    a0 = fmaf(__half2float(t[(size_t)s * IN_F + lane]), w, a0);
  }
  outb[(size_t)node * IN_F + lane] = __float2half_rn((a0 + a1) + (a2 + a3));
}

__global__ __launch_bounds__(256) void gather_h(
    const __half* __restrict__ t, const int* __restrict__ off,
    const unsigned int* __restrict__ csr, __half* __restrict__ outb) {
  const int node = blockIdx.x * 4 + (threadIdx.x >> 6);
  const int lane = threadIdx.x & 63;
  const __half2* __restrict__ tb = (const __half2*)t;
  const int p0 = off[node], p1 = off[node + 1];
  float2 a0 = make_float2(0.f, 0.f), a1 = make_float2(0.f, 0.f);
  float2 a2 = make_float2(0.f, 0.f), a3 = make_float2(0.f, 0.f);
  int p = p0;
  for (; p + 8 <= p1; p += 8) {
    int s0, s1, s2, s3, s4, s5, s6, s7;
    float w0, w1, w2, w3, w4, w5, w6, w7;
    unpack(csr[p], s0, w0);     unpack(csr[p + 1], s1, w1);
    unpack(csr[p + 2], s2, w2); unpack(csr[p + 3], s3, w3);
    unpack(csr[p + 4], s4, w4); unpack(csr[p + 5], s5, w5);
    unpack(csr[p + 6], s6, w6); unpack(csr[p + 7], s7, w7);
    const __half2 h0 = tb[(size_t)s0 * 64 + lane];
    const __half2 h1 = tb[(size_t)s1 * 64 + lane];
    const __half2 h2 = tb[(size_t)s2 * 64 + lane];
    const __half2 h3 = tb[(size_t)s3 * 64 + lane];
    const __half2 h4 = tb[(size_t)s4 * 64 + lane];
    const __half2 h5 = tb[(size_t)s5 * 64 + lane];
    const __half2 h6 = tb[(size_t)s6 * 64 + lane];
    const __half2 h7 = tb[(size_t)s7 * 64 + lane];
    float2 f;
    f = __half22float2(h0); a0.x = fmaf(f.x, w0, a0.x); a0.y = fmaf(f.y, w0, a0.y);
    f = __half22float2(h1); a1.x = fmaf(f.x, w1, a1.x); a1.y = fmaf(f.y, w1, a1.y);
    f = __half22float2(h2); a2.x = fmaf(f.x, w2, a2.x); a2.y = fmaf(f.y, w2, a2.y);
    f = __half22float2(h3); a3.x = fmaf(f.x, w3, a3.x); a3.y = fmaf(f.y, w3, a3.y);
    f = __half22float2(h4); a0.x = fmaf(f.x, w4, a0.x); a0.y = fmaf(f.y, w4, a0.y);
    f = __half22float2(h5); a1.x = fmaf(f.x, w5, a1.x); a1.y = fmaf(f.y, w5, a1.y);
    f = __half22float2(h6); a2.x = fmaf(f.x, w6, a2.x); a2.y = fmaf(f.y, w6, a2.y);
    f = __half22float2(h7); a3.x = fmaf(f.x, w7, a3.x); a3.y = fmaf(f.y, w7, a3.y);
  }
  for (; p < p1; ++p) {
    int s; float w;
    unpack(csr[p], s, w);
    const float2 f = __half22float2(tb[(size_t)s * 64 + lane]);
    a0.x = fmaf(f.x, w, a0.x); a0.y = fmaf(f.y, w, a0.y);
  }
  const float2 s = make_float2((a0.x + a1.x) + (a2.x + a3.x),
                               (a0.y + a1.y) + (a2.y + a3.y));
  ((__half2*)outb)[(size_t)node * 64 + lane] = __float22half2_rn(s);
}

// ---------------- head: one node per thread, 16 independent accumulators ----------------
__global__ __launch_bounds__(256) void head_kernel(
    const __half* __restrict__ h2raw, const float* __restrict__ b2,
    const float* __restrict__ Wm, const float* __restrict__ bm,
    float* __restrict__ sm_out, float* __restrict__ diag, int n) {
  __shared__ float Wl[H_F * K_C];   // 8 KB, [k][c]
  __shared__ float b2l[H_F];
  __shared__ float part[K_C];
  for (int t = threadIdx.x; t < H_F * K_C; t += 256) Wl[t] = Wm[t];
  if (threadIdx.x < H_F) b2l[threadIdx.x] = b2[threadIdx.x];
  if (threadIdx.x < K_C) part[threadIdx.x] = 0.f;
  __syncthreads();

  const int node = blockIdx.x * 256 + threadIdx.x;
  const int lane = threadIdx.x & 63;
  float acc[K_C];
#pragma unroll
  for (int c = 0; c < K_C; ++c) acc[c] = bm[c];

  if (node < n) {
    const __half2* __restrict__ hrow = (const __half2*)(h2raw + (size_t)node * H_F);
#pragma unroll 4
    for (int k2 = 0; k2 < H_F / 2; ++k2) {
      const float2 hv = __half22float2(hrow[k2]);
      const float h0 = fmaxf(hv.x + b2l[2 * k2], 0.f);
      const float h1 = fmaxf(hv.y + b2l[2 * k2 + 1], 0.f);
      const float4* __restrict__ w0 = (const float4*)(Wl + (2 * k2) * K_C);      // uniform
      const float4* __restrict__ w1 = (const float4*)(Wl + (2 * k2 + 1) * K_C);  // uniform
#pragma unroll
      for (int q = 0; q < 4; ++q) {
        const float4 a = w0[q], b = w1[q];
        acc[4 * q + 0] = fmaf(h0, a.x, acc[4 * q + 0]);
        acc[4 * q + 1] = fmaf(h0, a.y, acc[4 * q + 1]);
        acc[4 * q + 2] = fmaf(h0, a.z, acc[4 * q + 2]);
        acc[4 * q + 3] = fmaf(h0, a.w, acc[4 * q + 3]);
        acc[4 * q + 0] = fmaf(h1, b.x, acc[4 * q + 0]);
        acc[4 * q + 1] = fmaf(h1, b.y, acc[4 * q + 1]);
        acc[4 * q + 2] = fmaf(h1, b.z, acc[4 * q + 2]);
        acc[4 * q + 3] = fmaf(h1, b.w, acc[4 * q + 3]);
      }
    }
  }

  float mx = acc[0];
#pragma unroll
  for (int c = 1; c < K_C; ++c) mx = fmaxf(mx, acc[c]);
  float sum = 0.f;
#pragma unroll
  for (int c = 0; c < K_C; ++c) { acc[c] = __expf(acc[c] - mx); sum += acc[c]; }
  const float inv = 1.f / sum;
  float sq[K_C];
  if (node < n) {
#pragma unroll
    for (int c = 0; c < K_C; ++c) { acc[c] *= inv; sq[c] = acc[c] * acc[c]; }
    float4* o = (float4*)(sm_out + (size_t)node * K_C);
    o[0] = make_float4(acc[0], acc[1], acc[2], acc[3]);
    o[1] = make_float4(acc[4], acc[5], acc[6], acc[7]);
    o[2] = make_float4(acc[8], acc[9], acc[10], acc[11]);
    o[3] = make_float4(acc[12], acc[13], acc[14], acc[15]);
  } else {
#pragma unroll
    for (int c = 0; c < K_C; ++c) sq[c] = 0.f;
  }

#pragma unroll
  for (int c = 0; c < K_C; ++c) {
    float v = sq[c];
#pragma unroll
    for (int off = 32; off; off >>= 1) v += __shfl_xor(v, off);
    if (lane == 0) atomicAdd(&part[c], v);
  }
  __syncthreads();
  if (threadIdx.x < K_C) atomicAdd(&diag[threadIdx.x], part[threadIdx.x]);
}

__global__ void loss_kernel(const float* __restrict__ diag, float* __restrict__ out) {
  int c = threadIdx.x;
  float v = (c < K_C) ? sqrtf(diag[c] + 1e-15f) : 0.f;
#pragma unroll
  for (int off = 8; off; off >>= 1) v += __shfl_xor(v, off, 16);
  if (c == 0) out[0] = -v / sqrtf((float)N_NODES * (float)K_C);
}

extern "C" void kernel_launch(void* const* d_in, const int* in_sizes, int n_in,
                              void* d_out, int out_size, void* d_ws, size_t ws_size,
                              hipStream_t stream) {
  const float* x  = (const float*)d_in[0];
  const int*   ei = (const int*)d_in[1];
  const float* ew = (const float*)d_in[2];
  const float* W1 = (const float*)d_in[3];
  const float* b1 = (const float*)d_in[4];
  const float* W2 = (const float*)d_in[5];
  const float* b2 = (const float*)d_in[6];
  const float* Wm = (const float*)d_in[7];
  const float* bm = (const float*)d_in[8];
  float* out = (float*)d_out;

  const int* srcv = ei;
  const int* dstv = ei + E_EDGES;

  char* ws = (char*)d_ws;
  float*        diag    = (float*)ws;                        // 16 floats
  int*          bsum    = (int*)(ws + 256);                  // 64 ints
  int*          bcursor = (int*)(ws + 512);                  // NBUCK ints
  __half*       WT1     = (__half*)(ws + 4096);              // 128*64 fp16 (16 KB)
  __half*       WT2     = (__half*)(ws + 4096 + 16384);      // 128*128 fp16 (32 KB)
  int*          off     = (int*)(ws + 57344);                // N+1 ints
  int*          deg     = off + (N_NODES + 64);              // N ints
  unsigned int* csr     = (unsigned int*)(deg + N_NODES);    // E uints (3.2 MB)
  int2*         inter   = (int2*)(csr + E_EDGES);            // E int2 (6.4 MB)
  char*         bufA    = (char*)(inter + E_EDGES);          // 12.8 MB region
  char*         bufB    = bufA + (size_t)N_NODES * H_F * 2;  // 12.8 MB region

  __half* xh    = (__half*)bufB;   // fp16 x [N][64], dead after gather_x
  __half* aggxh = (__half*)bufA;   // fp16 A*x [N][64], dead after gemm64
  __half* h1h   = (__half*)bufB;   // fp16 h1 [N][128] (overwrites xh)
  __half* t2h   = (__half*)bufA;   // fp16 t2 [N][128] (overwrites aggxh)
  __half* h2h   = (__half*)bufB;   // fp16 h2 [N][128] (overwrites h1h)

  hipMemsetAsync(diag, 0, K_C * sizeof(float), stream);
  hipMemsetAsync(deg, 0, N_NODES * sizeof(int), stream);

  // weight prep (tiny)
  transposeW<IN_F><<<(IN_F * 128 + 255) / 256, 256, 0, stream>>>(W1, WT1);
  transposeW<H_F><<<(H_F * 128 + 255) / 256, 256, 0, stream>>>(W2, WT2);

  // CSR build: hist -> scan -> two-level counting sort
  hist_kernel<<<(E_EDGES + 255) / 256, 256, 0, stream>>>(dstv, deg);
  scan_local<<<NB, SCAN_B, 0, stream>>>(deg, off, bsum);
  scan_block<<<1, 64, 0, stream>>>(bsum);
  add_base<<<NB, SCAN_B, 0, stream>>>(off, bsum, bcursor);
  bin_pass<<<NCHUNK, 256, 0, stream>>>(srcv, dstv, ew, bcursor, inter);
  sort_pass<<<NBUCK, 256, 0, stream>>>(inter, off, csr);

  // layer 1 (reordered): xh = fp16(x); aggxh = A*xh; h1h = relu(aggxh @ W1 + b1)
  f2h_kernel<<<(N_NODES * IN_F / 4 + 255) / 256, 256, 0, stream>>>(x, xh, N_NODES * IN_F / 4);
  gather_x<<<N_NODES / 4, 256, 0, stream>>>(xh, off, csr, aggxh);
  gemm_mfma<IN_F, true><<<(N_NODES + 63) / 64, 256, 0, stream>>>(aggxh, WT1, b1, h1h, N_NODES);

  // layer 2: t2h = fp16(h1h @ W2); h2h = fp16(A * t2h)
  gemm_mfma<H_F, false><<<(N_NODES + 63) / 64, 256, 0, stream>>>(h1h, WT2, nullptr, t2h, N_NODES);
  gather_h<<<N_NODES / 4, 256, 0, stream>>>(t2h, off, csr, h2h);

  // head
  head_kernel<<<(N_NODES + 255) / 256, 256, 0, stream>>>(h2h, b2, Wm, bm, out, diag, N_NODES);
  loss_kernel<<<1, 64, 0, stream>>>(diag, out + (size_t)N_NODES * K_C);
}